// Round 1
// baseline (1814.439 us; speedup 1.0000x reference)
//
#include <hip/hip_runtime.h>
#include <math.h>

#define N_NODES 50000
#define N_EDGES 800000
#define NUM_GRAPHS 256
#define NPADROWS 50048   // 782*64
#define CAP 64           // CSR capacity per node (max observed degree ~35)

__device__ __forceinline__ float fast_rcp(float x) {
#if __has_builtin(__builtin_amdgcn_rcpf)
  return __builtin_amdgcn_rcpf(x);
#else
  return 1.0f / x;
#endif
}
__device__ __forceinline__ float sigm(float x) { return fast_rcp(1.0f + __expf(-x)); }
__device__ __forceinline__ float softp(float x) {
  return fmaxf(x, 0.0f) + __logf(1.0f + __expf(-fabsf(x)));
}

// x[n][0:128] = emb[atoms[n]], x[n][128] = pos.z, pad cols 129..131 = 0
__global__ void init_x(const int* __restrict__ atoms, const float* __restrict__ pos,
                       const float* __restrict__ emb, float* __restrict__ x) {
  int n = blockIdx.x;
  int t = threadIdx.x;
  if (n >= N_NODES) return;
  x[(size_t)n * 132 + t] = emb[atoms[n] * 128 + t];
  if (t == 0) x[(size_t)n * 132 + 128] = pos[n * 3 + 2];
  if (t >= 1 && t <= 3) x[(size_t)n * 132 + 128 + t] = 0.0f;
}

// Wpad[l][g][k][c], k,c in [0,132), zero-padded. g0=Wf rows0..128, g1=Wf rows129..257,
// g2=Ws rows0..128, g3=Ws rows129..257
__global__ void prep_w(const float* __restrict__ Wf, const float* __restrict__ Ws,
                       float* __restrict__ Wpad) {
  int idx = blockIdx.x * 256 + threadIdx.x;
  if (idx >= 5 * 4 * 132 * 132) return;
  int c = idx % 132;
  int k = (idx / 132) % 132;
  int g = (idx / (132 * 132)) % 4;
  int l = idx / (132 * 132 * 4);
  float v = 0.0f;
  if (c < 129 && k < 129) {
    const float* W = (g >= 2) ? Ws : Wf;
    int row = (g & 1) ? (129 + k) : k;
    v = W[(size_t)(l * 259 + row) * 129 + c];
  }
  Wpad[idx] = v;
}

// CSR build: slot = atomicAdd(cnt[dst]); also computes edge_attr
__global__ void build_csr(const int* __restrict__ ei, const float* __restrict__ pos,
                          int* __restrict__ cnt, int* __restrict__ csr_src,
                          float* __restrict__ csr_ea) {
  int e = blockIdx.x * 256 + threadIdx.x;
  if (e >= N_EDGES) return;
  int s = ei[e];
  int d = ei[N_EDGES + e];
  float dx = pos[s * 3 + 0] - pos[d * 3 + 0];
  float dy = pos[s * 3 + 1] - pos[d * 3 + 1];
  float dz = pos[s * 3 + 2] - pos[d * 3 + 2];
  float ea = sqrtf(dx * dx + dy * dy + dz * dz);
  int p = atomicAdd(&cnt[d], 1);
  if (p < CAP) {
    csr_src[d * CAP + p] = s;
    csr_ea[d * CAP + p] = ea;
  }
}

// P[n][g*132+c] for c in 0..127 : x(64 rows) @ Wpad block (132x132)
__global__ __launch_bounds__(256) void gemm_main(const float* __restrict__ X,
                                                 const float* __restrict__ Wpad,
                                                 float* __restrict__ P, int layer) {
  __shared__ float sm[64 * 132];
  int n0 = blockIdx.x * 64;
  int g = blockIdx.y;
  const float* Wg = Wpad + (size_t)(layer * 4 + g) * 132 * 132;
  for (int j = threadIdx.x; j < 64 * 33; j += 256) {
    int nl = j / 33, kq = j - nl * 33;
    float4 v = *(const float4*)(X + (size_t)(n0 + nl) * 132 + kq * 4);
    *(float4*)(&sm[nl * 132 + kq * 4]) = v;
  }
  __syncthreads();
  int tx = threadIdx.x & 31, ty = threadIdx.x >> 5;
  const float* a_base = &sm[ty * 8 * 132];
  float acc[8][4] = {};
#pragma unroll 4
  for (int k = 0; k < 132; ++k) {
    float4 b = *(const float4*)(Wg + k * 132 + tx * 4);
#pragma unroll
    for (int i = 0; i < 8; ++i) {
      float a = a_base[i * 132 + k];
      acc[i][0] += a * b.x;
      acc[i][1] += a * b.y;
      acc[i][2] += a * b.z;
      acc[i][3] += a * b.w;
    }
  }
#pragma unroll
  for (int i = 0; i < 8; ++i) {
    float4 v = make_float4(acc[i][0], acc[i][1], acc[i][2], acc[i][3]);
    *(float4*)(P + (size_t)(n0 + ty * 8 + i) * 528 + g * 132 + tx * 4) = v;
  }
}

// the odd column c=128 for all 4 groups
__global__ void gemm_col128(const float* __restrict__ X, const float* __restrict__ Wpad,
                            float* __restrict__ P, int layer) {
  int t = blockIdx.x * 256 + threadIdx.x;
  int node = t >> 2, g = t & 3;
  if (node >= N_NODES) return;
  const float* Wg = Wpad + (size_t)(layer * 4 + g) * 132 * 132 + 128;
  const float* xr = X + (size_t)node * 132;
  float s = 0.0f;
#pragma unroll 4
  for (int k = 0; k < 129; ++k) s += xr[k] * Wg[k * 132];
  P[(size_t)node * 528 + g * 132 + 128] = s;
}

// one wave per dst node; lanes over channels {lane, lane+64}, lane0 also ch128
__global__ __launch_bounds__(256) void edge_agg(
    const float* __restrict__ P, const float* __restrict__ x, float* __restrict__ xn,
    const int* __restrict__ cnt, const int* __restrict__ csr_src,
    const float* __restrict__ csr_ea, const float* __restrict__ WfL,
    const float* __restrict__ bfL, const float* __restrict__ WsL,
    const float* __restrict__ bsL) {
  int lane = threadIdx.x & 63;
  int n = blockIdx.x * 4 + (threadIdx.x >> 6);
  if (n >= N_NODES) return;
  const float* wfl = WfL + 258 * 129;  // last z row (edge_attr weight)
  const float* wsl = WsL + 258 * 129;
  const float* Pn = P + (size_t)n * 528;
  int c0 = lane, c1 = 64 + lane;
  float bf0 = Pn[c0] + bfL[c0], bf1 = Pn[c1] + bfL[c1];
  float bs0 = Pn[264 + c0] + bsL[c0], bs1 = Pn[264 + c1] + bsL[c1];
  float wf0 = wfl[c0], wf1 = wfl[c1], ws0 = wsl[c0], ws1 = wsl[c1];
  float acc0 = 0.0f, acc1 = 0.0f;
  float bf2 = 0.0f, bs2 = 0.0f, wf2 = 0.0f, ws2 = 0.0f, acc2 = 0.0f;
  if (lane == 0) {
    bf2 = Pn[128] + bfL[128];
    bs2 = Pn[264 + 128] + bsL[128];
    wf2 = wfl[128];
    ws2 = wsl[128];
  }
  int m = cnt[n];
  if (m > CAP) m = CAP;
  int base = n * CAP;
  for (int e = 0; e < m; ++e) {
    int s = csr_src[base + e];
    float ea = csr_ea[base + e];
    const float* Ps = P + (size_t)s * 528;
    float gf0 = bf0 + Ps[132 + c0] + ea * wf0;
    float gs0 = bs0 + Ps[396 + c0] + ea * ws0;
    float gf1 = bf1 + Ps[132 + c1] + ea * wf1;
    float gs1 = bs1 + Ps[396 + c1] + ea * ws1;
    acc0 += sigm(gf0) * softp(gs0);
    acc1 += sigm(gf1) * softp(gs1);
    if (lane == 0) {
      float gf2 = bf2 + Ps[132 + 128] + ea * wf2;
      float gs2 = bs2 + Ps[396 + 128] + ea * ws2;
      acc2 += sigm(gf2) * softp(gs2);
    }
  }
  size_t xo = (size_t)n * 132;
  xn[xo + c0] = x[xo + c0] + acc0;
  xn[xo + c1] = x[xo + c1] + acc1;
  if (lane == 0) xn[xo + 128] = x[xo + 128] + acc2;
  if (lane >= 1 && lane <= 3) xn[xo + 128 + lane] = 0.0f;
}

__global__ __launch_bounds__(256) void pool(const float* __restrict__ x,
                                            const int* __restrict__ batch,
                                            float* __restrict__ gsum, int* __restrict__ gcnt) {
  int lane = threadIdx.x & 63;
  int n = blockIdx.x * 4 + (threadIdx.x >> 6);
  if (n >= N_NODES) return;
  int b = batch[n];
  size_t xo = (size_t)n * 132;
  atomicAdd(&gsum[b * 132 + lane], x[xo + lane]);
  atomicAdd(&gsum[b * 132 + 64 + lane], x[xo + 64 + lane]);
  if (lane == 0) {
    atomicAdd(&gsum[b * 132 + 128], x[xo + 128]);
    atomicAdd(&gcnt[b], 1);
  }
}

// one block per graph; first layer divides by count (mean pooling)
__global__ void fc(const float* __restrict__ gin, const int* __restrict__ gcnt,
                   const float* __restrict__ W, const float* __restrict__ b,
                   float* __restrict__ gout, int divide) {
  __shared__ float row[132];
  int i = blockIdx.x;
  int t = threadIdx.x;
  if (t < 129) {
    float v = gin[i * 132 + t];
    if (divide) v *= fast_rcp(fmaxf((float)gcnt[i], 1.0f));
    row[t] = v;
  }
  __syncthreads();
  if (t < 129) {
    float s = b[t];
#pragma unroll 4
    for (int k = 0; k < 129; ++k) s += row[k] * W[k * 129 + t];
    gout[i * 132 + t] = s;
  }
}

__global__ void outk(const float* __restrict__ gin, const float* __restrict__ Wout,
                     const float* __restrict__ bout, float* __restrict__ out) {
  int i = threadIdx.x;  // 256 graphs, one block
  float s = bout[0];
#pragma unroll 4
  for (int k = 0; k < 129; ++k) s += gin[i * 132 + k] * Wout[k];
  out[i] = s;
}

extern "C" void kernel_launch(void* const* d_in, const int* in_sizes, int n_in,
                              void* d_out, int out_size, void* d_ws, size_t ws_size,
                              hipStream_t stream) {
  const int* atoms = (const int*)d_in[0];
  const float* pos = (const float*)d_in[1];
  const int* ei = (const int*)d_in[2];
  const int* batch = (const int*)d_in[3];
  const float* emb = (const float*)d_in[4];
  const float* Wf = (const float*)d_in[5];
  const float* bf = (const float*)d_in[6];
  const float* Ws = (const float*)d_in[7];
  const float* bs = (const float*)d_in[8];
  const float* Wfc = (const float*)d_in[9];
  const float* bfc = (const float*)d_in[10];
  const float* Wout = (const float*)d_in[11];
  const float* bout = (const float*)d_in[12];
  float* outp = (float*)d_out;

  float* ws = (float*)d_ws;
  float* x0 = ws;                                  // NPADROWS*132
  float* x1 = x0 + (size_t)NPADROWS * 132;         // NPADROWS*132
  float* P = x1 + (size_t)NPADROWS * 132;          // NPADROWS*528
  float* Wpad = P + (size_t)NPADROWS * 528;        // 5*4*132*132
  float* cea = Wpad + 5 * 4 * 132 * 132;           // N_NODES*CAP
  float* gsum = cea + (size_t)N_NODES * CAP;       // 256*132
  float* gA = gsum + 256 * 132;
  float* gB = gA + 256 * 132;
  int* cnt = (int*)(gB + 256 * 132);               // N_NODES
  int* csrs = cnt + N_NODES;                       // N_NODES*CAP
  int* gcnt = csrs + (size_t)N_NODES * CAP;        // 256

  hipMemsetAsync(cnt, 0, N_NODES * sizeof(int), stream);
  hipMemsetAsync(gsum, 0, 256 * 132 * sizeof(float), stream);
  hipMemsetAsync(gcnt, 0, 256 * sizeof(int), stream);

  init_x<<<N_NODES, 128, 0, stream>>>(atoms, pos, emb, x0);
  prep_w<<<(5 * 4 * 132 * 132 + 255) / 256, 256, 0, stream>>>(Wf, Ws, Wpad);
  build_csr<<<(N_EDGES + 255) / 256, 256, 0, stream>>>(ei, pos, cnt, csrs, cea);

  float* xin = x0;
  float* xout = x1;
  for (int l = 0; l < 5; ++l) {
    gemm_main<<<dim3(NPADROWS / 64, 4), 256, 0, stream>>>(xin, Wpad, P, l);
    gemm_col128<<<(N_NODES * 4 + 255) / 256, 256, 0, stream>>>(xin, Wpad, P, l);
    edge_agg<<<(N_NODES + 3) / 4, 256, 0, stream>>>(
        P, xin, xout, cnt, csrs, cea, Wf + (size_t)l * 259 * 129, bf + l * 129,
        Ws + (size_t)l * 259 * 129, bs + l * 129);
    float* t = xin; xin = xout; xout = t;
  }

  pool<<<(N_NODES + 3) / 4, 256, 0, stream>>>(xin, batch, gsum, gcnt);
  fc<<<NUM_GRAPHS, 192, 0, stream>>>(gsum, gcnt, Wfc, bfc, gA, 1);
  fc<<<NUM_GRAPHS, 192, 0, stream>>>(gA, gcnt, Wfc + 129 * 129, bfc + 129, gB, 0);
  fc<<<NUM_GRAPHS, 192, 0, stream>>>(gB, gcnt, Wfc + 2 * 129 * 129, bfc + 2 * 129, gA, 0);
  outk<<<1, 256, 0, stream>>>(gA, Wout, bout, outp);
}

// Round 2
// 1592.103 us; speedup vs baseline: 1.1396x; 1.1396x over previous
//
#include <hip/hip_runtime.h>
#include <math.h>

#define N_NODES 50000
#define N_EDGES 800000
#define NUM_GRAPHS 256
#define NPADROWS 50048   // 782*64
#define CAP 64           // CSR capacity per node (max observed degree ~35)
#define XS 132           // x row stride (floats)
#define PDS 264          // Pd row stride (floats): [0..131]=f(dst)+bf, [132..263]=s(dst)+bs
#define PSS 128          // Ps row stride (u32): packed (bf16 f | bf16 s), ch 0..127

__device__ __forceinline__ float fast_rcp(float x) {
#if __has_builtin(__builtin_amdgcn_rcpf)
  return __builtin_amdgcn_rcpf(x);
#else
  return 1.0f / x;
#endif
}
__device__ __forceinline__ float sigm(float x) { return fast_rcp(1.0f + __expf(-x)); }
__device__ __forceinline__ float softp(float x) {
  return fmaxf(x, 0.0f) + __logf(1.0f + __expf(-fabsf(x)));
}
// round-to-nearest-even f32 -> bf16 (finite inputs)
__device__ __forceinline__ unsigned f2bf(float x) {
  unsigned u = __float_as_uint(x);
  return (u + 0x7fffu + ((u >> 16) & 1u)) >> 16;
}
__device__ __forceinline__ unsigned pack2(float f, float s) {
  return (f2bf(f) << 16) | f2bf(s);
}

// x[n][0:128] = emb[atoms[n]], x[n][128] = pos.z, pad cols 129..131 = 0
__global__ void init_x(const int* __restrict__ atoms, const float* __restrict__ pos,
                       const float* __restrict__ emb, float* __restrict__ x) {
  int n = blockIdx.x;
  int t = threadIdx.x;
  if (n >= N_NODES) return;
  x[(size_t)n * XS + t] = emb[atoms[n] * 128 + t];
  if (t == 0) x[(size_t)n * XS + 128] = pos[n * 3 + 2];
  if (t >= 1 && t <= 3) x[(size_t)n * XS + 128 + t] = 0.0f;
}

// Wpad[l][g][k][c], k,c in [0,132), zero-padded. g0=Wf rows0..128, g1=Wf rows129..257,
// g2=Ws rows0..128, g3=Ws rows129..257
__global__ void prep_w(const float* __restrict__ Wf, const float* __restrict__ Ws,
                       float* __restrict__ Wpad) {
  int idx = blockIdx.x * 256 + threadIdx.x;
  if (idx >= 5 * 4 * 132 * 132) return;
  int c = idx % 132;
  int k = (idx / 132) % 132;
  int g = (idx / (132 * 132)) % 4;
  int l = idx / (132 * 132 * 4);
  float v = 0.0f;
  if (c < 129 && k < 129) {
    const float* W = (g >= 2) ? Ws : Wf;
    int row = (g & 1) ? (129 + k) : k;
    v = W[(size_t)(l * 259 + row) * 129 + c];
  }
  Wpad[idx] = v;
}

// CSR build: slot = atomicAdd(cnt[dst]); entry packs (src, edge_attr)
__global__ void build_csr(const int* __restrict__ ei, const float* __restrict__ pos,
                          int* __restrict__ cnt, int2* __restrict__ csr) {
  int e = blockIdx.x * 256 + threadIdx.x;
  if (e >= N_EDGES) return;
  int s = ei[e];
  int d = ei[N_EDGES + e];
  float dx = pos[s * 3 + 0] - pos[d * 3 + 0];
  float dy = pos[s * 3 + 1] - pos[d * 3 + 1];
  float dz = pos[s * 3 + 2] - pos[d * 3 + 2];
  float ea = sqrtf(dx * dx + dy * dy + dz * dz);
  int p = atomicAdd(&cnt[d], 1);
  if (p < CAP) csr[d * CAP + p] = make_int2(s, __float_as_int(ea));
}

// mode 0: g0 -> Pd[0..131] (+bf); mode 1: g2 -> Pd[132..263] (+bs);
// mode 2: g1 & g3 -> Ps packed bf16 pairs (cols 0..127)
__global__ __launch_bounds__(256) void gemm_main(const float* __restrict__ X,
                                                 const float* __restrict__ Wpad,
                                                 const float* __restrict__ bfL,
                                                 const float* __restrict__ bsL,
                                                 float* __restrict__ Pd,
                                                 unsigned* __restrict__ Ps, int layer) {
  __shared__ float sm[64 * 132];
  int n0 = blockIdx.x * 64;
  int mode = blockIdx.y;
  for (int j = threadIdx.x; j < 64 * 33; j += 256) {
    int nl = j / 33, kq = j - nl * 33;
    *(float4*)(&sm[nl * 132 + kq * 4]) = *(const float4*)(X + (size_t)(n0 + nl) * XS + kq * 4);
  }
  __syncthreads();
  int tx = threadIdx.x & 31, ty = threadIdx.x >> 5;
  const float* a_base = &sm[ty * 8 * 132];
  if (mode < 2) {
    const float* Wg = Wpad + (size_t)(layer * 4 + mode * 2) * 132 * 132;
    const float* bias = (mode == 0) ? bfL : bsL;
    float acc[8][4] = {};
#pragma unroll 4
    for (int k = 0; k < 132; ++k) {
      float4 b = *(const float4*)(Wg + k * 132 + tx * 4);
#pragma unroll
      for (int i = 0; i < 8; ++i) {
        float a = a_base[i * 132 + k];
        acc[i][0] += a * b.x;
        acc[i][1] += a * b.y;
        acc[i][2] += a * b.z;
        acc[i][3] += a * b.w;
      }
    }
    float4 bv = *(const float4*)(bias + tx * 4);
#pragma unroll
    for (int i = 0; i < 8; ++i) {
      float4 v = make_float4(acc[i][0] + bv.x, acc[i][1] + bv.y, acc[i][2] + bv.z,
                             acc[i][3] + bv.w);
      *(float4*)(Pd + (size_t)(n0 + ty * 8 + i) * PDS + mode * 132 + tx * 4) = v;
    }
  } else {
    const float* W1 = Wpad + (size_t)(layer * 4 + 1) * 132 * 132;
    const float* W3 = Wpad + (size_t)(layer * 4 + 3) * 132 * 132;
    float af[8][4] = {}, as_[8][4] = {};
#pragma unroll 2
    for (int k = 0; k < 132; ++k) {
      float4 b1 = *(const float4*)(W1 + k * 132 + tx * 4);
      float4 b3 = *(const float4*)(W3 + k * 132 + tx * 4);
#pragma unroll
      for (int i = 0; i < 8; ++i) {
        float a = a_base[i * 132 + k];
        af[i][0] += a * b1.x;
        af[i][1] += a * b1.y;
        af[i][2] += a * b1.z;
        af[i][3] += a * b1.w;
        as_[i][0] += a * b3.x;
        as_[i][1] += a * b3.y;
        as_[i][2] += a * b3.z;
        as_[i][3] += a * b3.w;
      }
    }
#pragma unroll
    for (int i = 0; i < 8; ++i) {
      uint4 u;
      u.x = pack2(af[i][0], as_[i][0]);
      u.y = pack2(af[i][1], as_[i][1]);
      u.z = pack2(af[i][2], as_[i][2]);
      u.w = pack2(af[i][3], as_[i][3]);
      *(uint4*)(Ps + (size_t)(n0 + ty * 8 + i) * PSS + tx * 4) = u;
    }
  }
}

// column 128 for all 4 groups; one thread per node
__global__ void gemm_col128(const float* __restrict__ X, const float* __restrict__ Wpad,
                            const float* __restrict__ bfL, const float* __restrict__ bsL,
                            float* __restrict__ Pd, unsigned* __restrict__ Ps128,
                            int layer) {
  int n = blockIdx.x * 256 + threadIdx.x;
  if (n >= N_NODES) return;
  const float* xr = X + (size_t)n * XS;
  const float* W = Wpad + (size_t)(layer * 4) * 132 * 132 + 128;
  float d0 = 0.f, d1 = 0.f, d2 = 0.f, d3 = 0.f;
#pragma unroll 4
  for (int k = 0; k < 129; ++k) {
    float a = xr[k];
    d0 += a * W[k * 132];
    d1 += a * W[132 * 132 + k * 132];
    d2 += a * W[2 * 132 * 132 + k * 132];
    d3 += a * W[3 * 132 * 132 + k * 132];
  }
  Pd[(size_t)n * PDS + 128] = d0 + bfL[128];
  Pd[(size_t)n * PDS + 260] = d2 + bsL[128];
  Ps128[n] = pack2(d1, d3);
}

// one wave per dst node; lane handles channels {2*lane, 2*lane+1}; ch128 via tail pass
__global__ __launch_bounds__(256) void edge_agg(
    const float* __restrict__ Pd, const unsigned* __restrict__ Ps,
    const unsigned* __restrict__ Ps128, const float* __restrict__ x,
    float* __restrict__ xn, const int* __restrict__ cnt, const int2* __restrict__ csr,
    const float* __restrict__ WfL, const float* __restrict__ WsL) {
  int lane = threadIdx.x & 63;
  int n = blockIdx.x * 4 + (threadIdx.x >> 6);
  if (n >= N_NODES) return;
  const float* wfl = WfL + 258 * 129;  // edge_attr weight row
  const float* wsl = WsL + 258 * 129;
  const float* Pn = Pd + (size_t)n * PDS;
  int ce = 2 * lane;
  float2 bfv = *(const float2*)(Pn + ce);        // bias already folded in
  float2 bsv = *(const float2*)(Pn + 132 + ce);
  float2 wfv = *(const float2*)(wfl + ce);
  float2 wsv = *(const float2*)(wsl + ce);
  float bf2 = Pn[128], bs2 = Pn[260], wf2 = wfl[128], ws2 = wsl[128];
  int m = cnt[n];
  if (m > CAP) m = CAP;
  const int2* cb = csr + n * CAP;
  float a0 = 0.f, a1 = 0.f;
  for (int e = 0; e < m; ++e) {
    int2 se = cb[e];  // wave-uniform -> scalar load
    int s = se.x;
    float ea = __int_as_float(se.y);
    uint2 p = *(const uint2*)(Ps + (size_t)s * PSS + ce);
    float f0 = __uint_as_float(p.x & 0xffff0000u);
    float s0 = __uint_as_float(p.x << 16);
    float f1 = __uint_as_float(p.y & 0xffff0000u);
    float s1 = __uint_as_float(p.y << 16);
    float gf0 = bfv.x + f0 + ea * wfv.x;
    float gs0 = bsv.x + s0 + ea * wsv.x;
    float gf1 = bfv.y + f1 + ea * wfv.y;
    float gs1 = bsv.y + s1 + ea * wsv.y;
    a0 += sigm(gf0) * softp(gs0);
    a1 += sigm(gf1) * softp(gs1);
  }
  // channel 128: lanes parallel over edges (deg <= CAP = 64), then reduce
  float v2 = 0.f;
  if (lane < m) {
    int2 se = cb[lane];
    float ea = __int_as_float(se.y);
    unsigned p = Ps128[se.x];
    float f2 = __uint_as_float(p & 0xffff0000u);
    float s2 = __uint_as_float(p << 16);
    v2 = sigm(bf2 + f2 + ea * wf2) * softp(bs2 + s2 + ea * ws2);
  }
#pragma unroll
  for (int off = 32; off; off >>= 1) v2 += __shfl_down(v2, off, 64);
  size_t xo = (size_t)n * XS;
  float2 xv = *(const float2*)(x + xo + ce);
  float2 res = make_float2(xv.x + a0, xv.y + a1);
  *(float2*)(xn + xo + ce) = res;
  if (lane == 0) xn[xo + 128] = x[xo + 128] + v2;
  if (lane >= 1 && lane <= 3) xn[xo + 128 + lane] = 0.0f;
}

__global__ __launch_bounds__(256) void pool(const float* __restrict__ x,
                                            const int* __restrict__ batch,
                                            float* __restrict__ gsum, int* __restrict__ gcnt) {
  int lane = threadIdx.x & 63;
  int n = blockIdx.x * 4 + (threadIdx.x >> 6);
  if (n >= N_NODES) return;
  int b = batch[n];
  size_t xo = (size_t)n * XS;
  atomicAdd(&gsum[b * 132 + lane], x[xo + lane]);
  atomicAdd(&gsum[b * 132 + 64 + lane], x[xo + 64 + lane]);
  if (lane == 0) {
    atomicAdd(&gsum[b * 132 + 128], x[xo + 128]);
    atomicAdd(&gcnt[b], 1);
  }
}

// one block per graph; first layer divides by count (mean pooling)
__global__ void fc(const float* __restrict__ gin, const int* __restrict__ gcnt,
                   const float* __restrict__ W, const float* __restrict__ b,
                   float* __restrict__ gout, int divide) {
  __shared__ float row[132];
  int i = blockIdx.x;
  int t = threadIdx.x;
  if (t < 129) {
    float v = gin[i * 132 + t];
    if (divide) v *= fast_rcp(fmaxf((float)gcnt[i], 1.0f));
    row[t] = v;
  }
  __syncthreads();
  if (t < 129) {
    float s = b[t];
#pragma unroll 4
    for (int k = 0; k < 129; ++k) s += row[k] * W[k * 129 + t];
    gout[i * 132 + t] = s;
  }
}

__global__ void outk(const float* __restrict__ gin, const float* __restrict__ Wout,
                     const float* __restrict__ bout, float* __restrict__ out) {
  int i = threadIdx.x;  // 256 graphs, one block
  float s = bout[0];
#pragma unroll 4
  for (int k = 0; k < 129; ++k) s += gin[i * 132 + k] * Wout[k];
  out[i] = s;
}

extern "C" void kernel_launch(void* const* d_in, const int* in_sizes, int n_in,
                              void* d_out, int out_size, void* d_ws, size_t ws_size,
                              hipStream_t stream) {
  const int* atoms = (const int*)d_in[0];
  const float* pos = (const float*)d_in[1];
  const int* ei = (const int*)d_in[2];
  const int* batch = (const int*)d_in[3];
  const float* emb = (const float*)d_in[4];
  const float* Wf = (const float*)d_in[5];
  const float* bf = (const float*)d_in[6];
  const float* Ws = (const float*)d_in[7];
  const float* bs = (const float*)d_in[8];
  const float* Wfc = (const float*)d_in[9];
  const float* bfc = (const float*)d_in[10];
  const float* Wout = (const float*)d_in[11];
  const float* bout = (const float*)d_in[12];
  float* outp = (float*)d_out;

  float* ws = (float*)d_ws;
  float* x0 = ws;                                     // NPADROWS*XS
  float* x1 = x0 + (size_t)NPADROWS * XS;             // NPADROWS*XS
  float* Pd = x1 + (size_t)NPADROWS * XS;             // NPADROWS*PDS
  unsigned* Ps = (unsigned*)(Pd + (size_t)NPADROWS * PDS);  // NPADROWS*PSS
  unsigned* Ps128 = Ps + (size_t)NPADROWS * PSS;      // NPADROWS
  float* Wpad = (float*)(Ps128 + NPADROWS);           // 5*4*132*132
  float* gsum = Wpad + 5 * 4 * 132 * 132;             // 256*132
  float* gA = gsum + 256 * 132;
  float* gB = gA + 256 * 132;
  int* cnt = (int*)(gB + 256 * 132);                  // N_NODES
  int2* csr = (int2*)(cnt + N_NODES);                 // N_NODES*CAP int2 (8B aligned)
  int* gcnt = (int*)(csr + (size_t)N_NODES * CAP);    // 256

  hipMemsetAsync(cnt, 0, N_NODES * sizeof(int), stream);
  hipMemsetAsync(gsum, 0, 256 * 132 * sizeof(float), stream);
  hipMemsetAsync(gcnt, 0, 256 * sizeof(int), stream);

  init_x<<<N_NODES, 128, 0, stream>>>(atoms, pos, emb, x0);
  prep_w<<<(5 * 4 * 132 * 132 + 255) / 256, 256, 0, stream>>>(Wf, Ws, Wpad);
  build_csr<<<(N_EDGES + 255) / 256, 256, 0, stream>>>(ei, pos, cnt, csr);

  float* xin = x0;
  float* xout = x1;
  for (int l = 0; l < 5; ++l) {
    gemm_main<<<dim3(NPADROWS / 64, 3), 256, 0, stream>>>(xin, Wpad, bf + l * 129,
                                                          bs + l * 129, Pd, Ps, l);
    gemm_col128<<<(N_NODES + 255) / 256, 256, 0, stream>>>(xin, Wpad, bf + l * 129,
                                                           bs + l * 129, Pd, Ps128, l);
    edge_agg<<<(N_NODES + 3) / 4, 256, 0, stream>>>(Pd, Ps, Ps128, xin, xout, cnt, csr,
                                                    Wf + (size_t)l * 259 * 129,
                                                    Ws + (size_t)l * 259 * 129);
    float* t = xin; xin = xout; xout = t;
  }

  pool<<<(N_NODES + 3) / 4, 256, 0, stream>>>(xin, batch, gsum, gcnt);
  fc<<<NUM_GRAPHS, 192, 0, stream>>>(gsum, gcnt, Wfc, bfc, gA, 1);
  fc<<<NUM_GRAPHS, 192, 0, stream>>>(gA, gcnt, Wfc + 129 * 129, bfc + 129, gB, 0);
  fc<<<NUM_GRAPHS, 192, 0, stream>>>(gB, gcnt, Wfc + 2 * 129 * 129, bfc + 2 * 129, gA, 0);
  outk<<<1, 256, 0, stream>>>(gA, Wout, bout, outp);
}

// Round 3
// 1090.652 us; speedup vs baseline: 1.6636x; 1.4598x over previous
//
#include <hip/hip_runtime.h>
#include <math.h>

#define N_NODES 50000
#define N_EDGES 800000
#define NUM_GRAPHS 256
#define NPADROWS 50048   // 1564*32
#define CAP 64           // CSR capacity per node (max observed degree ~35)
#define XS 132           // xf row stride (floats); [0..127]=emb ch, [128]=z
#define PDS 264          // Pd row stride: [0..128]=f(dst)+bf, [132..260]=s(dst)+bs

typedef __attribute__((ext_vector_type(8))) short short8;
typedef __attribute__((ext_vector_type(4))) float f32x4;

__device__ __forceinline__ float fast_rcp(float x) {
#if __has_builtin(__builtin_amdgcn_rcpf)
  return __builtin_amdgcn_rcpf(x);
#else
  return 1.0f / x;
#endif
}
__device__ __forceinline__ float sigm(float x) { return fast_rcp(1.0f + __expf(-x)); }
__device__ __forceinline__ float softp(float x) {
  return fmaxf(x, 0.0f) + __logf(1.0f + __expf(-fabsf(x)));
}
// round-to-nearest-even f32 -> bf16 bits
__device__ __forceinline__ unsigned f2bf(float x) {
  unsigned u = __float_as_uint(x);
  return (u + 0x7fffu + ((u >> 16) & 1u)) >> 16;
}

// xf[n][0:128]=emb, xf[n][128]=pos.z ; xb packed bf16 pairs (64 u32/row)
__global__ void init_x(const int* __restrict__ atoms, const float* __restrict__ pos,
                       const float* __restrict__ emb, float* __restrict__ xf,
                       unsigned* __restrict__ xbu) {
  int n = blockIdx.x;  // 64 threads
  int t = threadIdx.x;
  int a = atoms[n];
  float2 e = *(const float2*)(emb + (size_t)a * 128 + 2 * t);
  xf[(size_t)n * XS + 2 * t] = e.x;
  xf[(size_t)n * XS + 2 * t + 1] = e.y;
  xbu[(size_t)n * 64 + t] = f2bf(e.x) | (f2bf(e.y) << 16);
  if (t == 0) xf[(size_t)n * XS + 128] = pos[n * 3 + 2];
}

// B packed in exact MFMA B-fragment order:
// Bp[((l*4+g)*9+ct)*4+ks][lane] = 8 bf16: B[k=ks*32+(lane>>4)*8+j][col=ct*16+(lane&15)]
// g0=Wf rows0..128 (dst), g1=Wf rows129..256 (src), g2/g3 same for Ws. K = x channels 0..127.
__global__ void prep_b(const float* __restrict__ Wf, const float* __restrict__ Ws,
                       uint4* __restrict__ Bp) {
  int idx = blockIdx.x * 256 + threadIdx.x;
  if (idx >= 5 * 4 * 9 * 4 * 64) return;
  int lane = idx & 63;
  int t = idx >> 6;
  int ks = t & 3; t >>= 2;
  int ct = t % 9; t /= 9;
  int g = t & 3;
  int l = t >> 2;
  const float* W = (g >= 2) ? Ws : Wf;
  int col = ct * 16 + (lane & 15);
  int kb = ks * 32 + (lane >> 4) * 8;
  unsigned u[4];
#pragma unroll
  for (int p = 0; p < 4; ++p) {
    unsigned lo = 0, hi = 0;
    if (col < 129) {
      int k0 = kb + 2 * p, k1 = k0 + 1;
      int r0 = (g & 1) ? 129 + k0 : k0;
      int r1 = (g & 1) ? 129 + k1 : k1;
      lo = f2bf(W[(size_t)(l * 259 + r0) * 129 + col]);
      hi = f2bf(W[(size_t)(l * 259 + r1) * 129 + col]);
    }
    u[p] = lo | (hi << 16);
  }
  Bp[idx] = make_uint4(u[0], u[1], u[2], u[3]);
}

// rank-1 row: W128[(l*4+g)*129 + c] = W[k=128 row][c]  (row 128 dst-side, 257 src-side)
__global__ void prep_w128(const float* __restrict__ Wf, const float* __restrict__ Ws,
                          float* __restrict__ W128) {
  int idx = blockIdx.x * 256 + threadIdx.x;
  if (idx >= 5 * 4 * 129) return;
  int c = idx % 129;
  int t = idx / 129;
  int g = t & 3;
  int l = t >> 2;
  const float* W = (g >= 2) ? Ws : Wf;
  int row = (g & 1) ? 257 : 128;
  W128[(l * 4 + g) * 129 + c] = W[(size_t)(l * 259 + row) * 129 + c];
}

__global__ void build_csr(const int* __restrict__ ei, const float* __restrict__ pos,
                          int* __restrict__ cnt, int2* __restrict__ csr) {
  int e = blockIdx.x * 256 + threadIdx.x;
  if (e >= N_EDGES) return;
  int s = ei[e];
  int d = ei[N_EDGES + e];
  float dx = pos[s * 3 + 0] - pos[d * 3 + 0];
  float dy = pos[s * 3 + 1] - pos[d * 3 + 1];
  float dz = pos[s * 3 + 2] - pos[d * 3 + 2];
  float ea = sqrtf(dx * dx + dy * dy + dz * dz);
  int p = atomicAdd(&cnt[d], 1);
  if (p < CAP) csr[d * CAP + p] = make_int2(s, __float_as_int(ea));
}

// graph start offsets from sorted batch (handles empty graphs); goff[256]=N sentinel
__global__ void offsets_k(const int* __restrict__ batch, int* __restrict__ goff) {
  int n = blockIdx.x * 256 + threadIdx.x;
  if (n > N_NODES) return;
  int b = (n < N_NODES) ? batch[n] : NUM_GRAPHS;
  int bp = (n > 0) ? batch[n - 1] : -1;
  for (int g = bp + 1; g <= b; ++g) goff[g] = n;
}

// 32 rows x (4 groups x 144 cols) per block; wave w = group w.
// K=128 MFMA over bf16 xb + rank-1 (x128 * W128row) epilogue; biases folded dst-side.
__global__ __launch_bounds__(256) void gemm_mfma(
    const unsigned* __restrict__ xbu, const float* __restrict__ xf,
    const uint4* __restrict__ Bp, const float* __restrict__ W128,
    const float* __restrict__ bfL, const float* __restrict__ bsL,
    float* __restrict__ Pd, unsigned short* __restrict__ Psf,
    unsigned short* __restrict__ Pss, unsigned short* __restrict__ Psf128,
    unsigned short* __restrict__ Pss128, int layer) {
  __shared__ short smA[32 * 136];  // row stride 136 shorts = 272 B (conflict-free b128)
  int n0 = blockIdx.x * 32;
  int tid = threadIdx.x;
  for (int ch = tid; ch < 512; ch += 256) {
    int row = ch >> 4, cq = ch & 15;
    *(uint4*)(&smA[row * 136 + cq * 8]) =
        *(const uint4*)(xbu + (size_t)(n0 + row) * 64 + cq * 4);
  }
  __syncthreads();
  int g = tid >> 6;
  int l = tid & 63;
  int q = l >> 4, c16 = l & 15;
  const short8* Bp8 = (const short8*)Bp;
  int bbase = (layer * 4 + g) * 9 * 4;
  f32x4 acc[2][9];
#pragma unroll
  for (int rt = 0; rt < 2; ++rt)
#pragma unroll
    for (int ct = 0; ct < 9; ++ct) acc[rt][ct] = (f32x4){0.f, 0.f, 0.f, 0.f};
#pragma unroll
  for (int ks = 0; ks < 4; ++ks) {
    short8 a0 = *(const short8*)(&smA[c16 * 136 + (ks * 4 + q) * 8]);
    short8 a1 = *(const short8*)(&smA[(16 + c16) * 136 + (ks * 4 + q) * 8]);
#pragma unroll
    for (int ct = 0; ct < 9; ++ct) {
      short8 b = Bp8[(size_t)(bbase + ct * 4 + ks) * 64 + l];
      acc[0][ct] = __builtin_amdgcn_mfma_f32_16x16x32_bf16(a0, b, acc[0][ct], 0, 0, 0);
      acc[1][ct] = __builtin_amdgcn_mfma_f32_16x16x32_bf16(a1, b, acc[1][ct], 0, 0, 0);
    }
  }
  const float* W1g = W128 + (layer * 4 + g) * 129;
  float x128[2][4];
#pragma unroll
  for (int rt = 0; rt < 2; ++rt)
#pragma unroll
    for (int r = 0; r < 4; ++r)
      x128[rt][r] = xf[(size_t)(n0 + rt * 16 + q * 4 + r) * XS + 128];
#pragma unroll
  for (int ct = 0; ct < 9; ++ct) {
    int col = ct * 16 + c16;
    float w1 = (col <= 128) ? W1g[col] : 0.0f;
    float bias = 0.0f;
    if (g == 0 && col <= 128) bias = bfL[col];
    if (g == 2 && col <= 128) bias = bsL[col];
#pragma unroll
    for (int rt = 0; rt < 2; ++rt) {
#pragma unroll
      for (int r = 0; r < 4; ++r) {
        int row = n0 + rt * 16 + q * 4 + r;
        float v = acc[rt][ct][r] + x128[rt][r] * w1 + bias;
        if (g == 0) {
          if (col <= 128) Pd[(size_t)row * PDS + col] = v;
        } else if (g == 2) {
          if (col <= 128) Pd[(size_t)row * PDS + 132 + col] = v;
        } else if (g == 1) {
          if (col < 128) Psf[(size_t)row * 128 + col] = (unsigned short)f2bf(v);
          else if (col == 128) Psf128[row] = (unsigned short)f2bf(v);
        } else {
          if (col < 128) Pss[(size_t)row * 128 + col] = (unsigned short)f2bf(v);
          else if (col == 128) Pss128[row] = (unsigned short)f2bf(v);
        }
      }
    }
  }
}

// one wave per dst node; lane = channels {2l, 2l+1}; residual update in place.
__global__ __launch_bounds__(256) void edge_agg(
    const float* __restrict__ Pd, const unsigned* __restrict__ Psfu,
    const unsigned* __restrict__ Pssu, const unsigned short* __restrict__ Psf128,
    const unsigned short* __restrict__ Pss128, float* __restrict__ xf,
    unsigned* __restrict__ xbu, const int* __restrict__ cnt,
    const int2* __restrict__ csr, const float* __restrict__ WfL,
    const float* __restrict__ WsL) {
  int lane = threadIdx.x & 63;
  int n = blockIdx.x * 4 + (threadIdx.x >> 6);
  if (n >= N_NODES) return;
  const float* wfl = WfL + 258 * 129;
  const float* wsl = WsL + 258 * 129;
  const float* Pn = Pd + (size_t)n * PDS;
  int ce = 2 * lane;
  float2 bfv = *(const float2*)(Pn + ce);
  float2 bsv = *(const float2*)(Pn + 132 + ce);
  float2 wfv = *(const float2*)(wfl + ce);
  float2 wsv = *(const float2*)(wsl + ce);
  float bf2 = Pn[128], bs2 = Pn[260], wf2 = wfl[128], ws2 = wsl[128];
  int m = cnt[n];
  if (m > CAP) m = CAP;
  const int2* cb = csr + n * CAP;
  float a0 = 0.f, a1 = 0.f;
  for (int e = 0; e < m; ++e) {
    int2 se = cb[e];
    int s = se.x;
    float ea = __int_as_float(se.y);
    unsigned pf = Psfu[(size_t)s * 64 + lane];
    unsigned ps = Pssu[(size_t)s * 64 + lane];
    float f0 = __uint_as_float(pf << 16);
    float f1 = __uint_as_float(pf & 0xffff0000u);
    float s0 = __uint_as_float(ps << 16);
    float s1 = __uint_as_float(ps & 0xffff0000u);
    a0 += sigm(bfv.x + f0 + ea * wfv.x) * softp(bsv.x + s0 + ea * wsv.x);
    a1 += sigm(bfv.y + f1 + ea * wfv.y) * softp(bsv.y + s1 + ea * wsv.y);
  }
  float v2 = 0.f;
  if (lane < m) {
    int2 se = cb[lane];
    float ea = __int_as_float(se.y);
    float f2 = __uint_as_float(((unsigned)Psf128[se.x]) << 16);
    float s2 = __uint_as_float(((unsigned)Pss128[se.x]) << 16);
    v2 = sigm(bf2 + f2 + ea * wf2) * softp(bs2 + s2 + ea * ws2);
  }
#pragma unroll
  for (int off = 32; off; off >>= 1) v2 += __shfl_down(v2, off, 64);
  size_t xo = (size_t)n * XS;
  float2 xv = *(const float2*)(xf + xo + ce);
  float2 res = make_float2(xv.x + a0, xv.y + a1);
  *(float2*)(xf + xo + ce) = res;
  xbu[(size_t)n * 64 + lane] = f2bf(res.x) | (f2bf(res.y) << 16);
  if (lane == 0) xf[xo + 128] += v2;
}

// one block per graph over its contiguous node range; writes the MEAN directly
__global__ void pool2(const float* __restrict__ xf, const int* __restrict__ goff,
                      float* __restrict__ gsum) {
  int gph = blockIdx.x;
  int t = threadIdx.x;
  if (t >= 129) return;
  int s = goff[gph], e = goff[gph + 1];
  float acc = 0.f;
  for (int n = s; n < e; ++n) acc += xf[(size_t)n * XS + t];
  gsum[gph * XS + t] = acc * fast_rcp(fmaxf((float)(e - s), 1.0f));
}

__global__ void fc(const float* __restrict__ gin, const float* __restrict__ W,
                   const float* __restrict__ b, float* __restrict__ gout) {
  __shared__ float row[132];
  int i = blockIdx.x;
  int t = threadIdx.x;
  if (t < 129) row[t] = gin[i * XS + t];
  __syncthreads();
  if (t < 129) {
    float s = b[t];
#pragma unroll 4
    for (int k = 0; k < 129; ++k) s += row[k] * W[k * 129 + t];
    gout[i * XS + t] = s;
  }
}

__global__ void outk(const float* __restrict__ gin, const float* __restrict__ Wout,
                     const float* __restrict__ bout, float* __restrict__ out) {
  int i = threadIdx.x;  // 256 graphs
  float s = bout[0];
#pragma unroll 4
  for (int k = 0; k < 129; ++k) s += gin[i * XS + k] * Wout[k];
  out[i] = s;
}

extern "C" void kernel_launch(void* const* d_in, const int* in_sizes, int n_in,
                              void* d_out, int out_size, void* d_ws, size_t ws_size,
                              hipStream_t stream) {
  const int* atoms = (const int*)d_in[0];
  const float* pos = (const float*)d_in[1];
  const int* ei = (const int*)d_in[2];
  const int* batch = (const int*)d_in[3];
  const float* emb = (const float*)d_in[4];
  const float* Wf = (const float*)d_in[5];
  const float* bfp = (const float*)d_in[6];
  const float* Ws = (const float*)d_in[7];
  const float* bsp = (const float*)d_in[8];
  const float* Wfc = (const float*)d_in[9];
  const float* bfc = (const float*)d_in[10];
  const float* Wout = (const float*)d_in[11];
  const float* bout = (const float*)d_in[12];
  float* outp = (float*)d_out;

  // workspace layout (16B-aligned head)
  uint4* Bp = (uint4*)d_ws;                                   // 46080 uint4
  float* xf = (float*)(Bp + 46080);                           // NPADROWS*132
  float* Pd = xf + (size_t)NPADROWS * XS;                     // NPADROWS*264
  unsigned* xbu = (unsigned*)(Pd + (size_t)NPADROWS * PDS);   // NPADROWS*64
  unsigned* Psfu = xbu + (size_t)NPADROWS * 64;               // NPADROWS*64
  unsigned* Pssu = Psfu + (size_t)NPADROWS * 64;              // NPADROWS*64
  float* W128 = (float*)(Pssu + (size_t)NPADROWS * 64);       // 2580
  float* gsum = W128 + 2580;                                  // 256*132
  float* gA = gsum + 256 * XS;
  float* gB = gA + 256 * XS;
  int* goff = (int*)(gB + 256 * XS);                          // 258 (padded)
  int* cnt = goff + 258;                                      // N_NODES
  int2* csr = (int2*)(cnt + N_NODES);                         // N_NODES*CAP
  unsigned short* Psf128 = (unsigned short*)(csr + (size_t)N_NODES * CAP);
  unsigned short* Pss128 = Psf128 + NPADROWS;

  hipMemsetAsync(cnt, 0, N_NODES * sizeof(int), stream);

  init_x<<<N_NODES, 64, 0, stream>>>(atoms, pos, emb, xf, xbu);
  prep_b<<<(5 * 4 * 9 * 4 * 64 + 255) / 256, 256, 0, stream>>>(Wf, Ws, Bp);
  prep_w128<<<(5 * 4 * 129 + 255) / 256, 256, 0, stream>>>(Wf, Ws, W128);
  build_csr<<<(N_EDGES + 255) / 256, 256, 0, stream>>>(ei, pos, cnt, csr);
  offsets_k<<<(N_NODES + 256) / 256, 256, 0, stream>>>(batch, goff);

  for (int l = 0; l < 5; ++l) {
    gemm_mfma<<<NPADROWS / 32, 256, 0, stream>>>(xbu, xf, Bp, W128, bfp + l * 129,
                                                 bsp + l * 129, Pd, Psf128 ? (unsigned short*)Psfu : 0,
                                                 (unsigned short*)Pssu, Psf128, Pss128, l);
    edge_agg<<<(N_NODES + 3) / 4, 256, 0, stream>>>(Pd, Psfu, Pssu, Psf128, Pss128, xf,
                                                    xbu, cnt, csr,
                                                    Wf + (size_t)l * 259 * 129,
                                                    Ws + (size_t)l * 259 * 129);
  }

  pool2<<<NUM_GRAPHS, 192, 0, stream>>>(xf, goff, gsum);
  fc<<<NUM_GRAPHS, 192, 0, stream>>>(gsum, Wfc, bfc, gA);
  fc<<<NUM_GRAPHS, 192, 0, stream>>>(gA, Wfc + 129 * 129, bfc + 129, gB);
  fc<<<NUM_GRAPHS, 192, 0, stream>>>(gB, Wfc + 2 * 129 * 129, bfc + 2 * 129, gA);
  outk<<<1, 256, 0, stream>>>(gA, Wout, bout, outp);
}

// Round 4
// 871.597 us; speedup vs baseline: 2.0817x; 1.2513x over previous
//
#include <hip/hip_runtime.h>
#include <math.h>

#define N_NODES 50000
#define N_EDGES 800000
#define NUM_GRAPHS 256
#define NPADROWS 50048   // 1564*32
#define CAP 64           // CSR capacity per node (max observed degree ~35)
#define XS 132           // xf row stride (floats); [0..127]=emb ch, [128]=z
#define PDS 264          // Pd row stride: [0..128]=S*(f(dst)+bf), [132..260]=S*(s(dst)+bs)
#define SCL -1.44269504088896f   // -log2(e): exp2(SCL*x) = exp(-x)
#define C693 0.69314718056f

typedef __attribute__((ext_vector_type(8))) short short8;
typedef __attribute__((ext_vector_type(4))) float f32x4;

__device__ __forceinline__ float fast_rcp(float x) {
#if __has_builtin(__builtin_amdgcn_rcpf)
  return __builtin_amdgcn_rcpf(x);
#else
  return 1.0f / x;
#endif
}
__device__ __forceinline__ float EX2(float x) {
#if __has_builtin(__builtin_amdgcn_exp2f)
  return __builtin_amdgcn_exp2f(x);
#else
  return exp2f(x);
#endif
}
__device__ __forceinline__ float LG2(float x) {
#if __has_builtin(__builtin_amdgcn_logf)
  return __builtin_amdgcn_logf(x);  // log2
#else
  return log2f(x);
#endif
}
// round-to-nearest-even f32 -> bf16 bits
__device__ __forceinline__ unsigned f2bf(float x) {
  unsigned u = __float_as_uint(x);
  return (u + 0x7fffu + ((u >> 16) & 1u)) >> 16;
}
__device__ __forceinline__ float u2f(unsigned u) { return __uint_as_float(u); }

// xf[n][0:128]=emb, xf[n][128]=pos.z ; xb packed bf16 pairs (64 u32/row)
__global__ void init_x(const int* __restrict__ atoms, const float* __restrict__ pos,
                       const float* __restrict__ emb, float* __restrict__ xf,
                       unsigned* __restrict__ xbu) {
  int n = blockIdx.x;  // 64 threads
  int t = threadIdx.x;
  int a = atoms[n];
  float2 e = *(const float2*)(emb + (size_t)a * 128 + 2 * t);
  xf[(size_t)n * XS + 2 * t] = e.x;
  xf[(size_t)n * XS + 2 * t + 1] = e.y;
  xbu[(size_t)n * 64 + t] = f2bf(e.x) | (f2bf(e.y) << 16);
  if (t == 0) xf[(size_t)n * XS + 128] = pos[n * 3 + 2];
}

// B packed in exact MFMA B-fragment order:
// Bp[((l*4+g)*9+ct)*4+ks][lane] = 8 bf16: B[k=ks*32+(lane>>4)*8+j][col=ct*16+(lane&15)]
__global__ void prep_b(const float* __restrict__ Wf, const float* __restrict__ Ws,
                       uint4* __restrict__ Bp) {
  int idx = blockIdx.x * 256 + threadIdx.x;
  if (idx >= 5 * 4 * 9 * 4 * 64) return;
  int lane = idx & 63;
  int t = idx >> 6;
  int ks = t & 3; t >>= 2;
  int ct = t % 9; t /= 9;
  int g = t & 3;
  int l = t >> 2;
  const float* W = (g >= 2) ? Ws : Wf;
  int col = ct * 16 + (lane & 15);
  int kb = ks * 32 + (lane >> 4) * 8;
  unsigned u[4];
#pragma unroll
  for (int p = 0; p < 4; ++p) {
    unsigned lo = 0, hi = 0;
    if (col < 129) {
      int k0 = kb + 2 * p, k1 = k0 + 1;
      int r0 = (g & 1) ? 129 + k0 : k0;
      int r1 = (g & 1) ? 129 + k1 : k1;
      lo = f2bf(W[(size_t)(l * 259 + r0) * 129 + col]);
      hi = f2bf(W[(size_t)(l * 259 + r1) * 129 + col]);
    }
    u[p] = lo | (hi << 16);
  }
  Bp[idx] = make_uint4(u[0], u[1], u[2], u[3]);
}

// rank-1 row: W128[(l*4+g)*129 + c] = W[k=128][c] (dst) or W[k=257][c] (src)
__global__ void prep_w128(const float* __restrict__ Wf, const float* __restrict__ Ws,
                          float* __restrict__ W128) {
  int idx = blockIdx.x * 256 + threadIdx.x;
  if (idx >= 5 * 4 * 129) return;
  int c = idx % 129;
  int t = idx / 129;
  int g = t & 3;
  int l = t >> 2;
  const float* W = (g >= 2) ? Ws : Wf;
  int row = (g & 1) ? 257 : 128;
  W128[(l * 4 + g) * 129 + c] = W[(size_t)(l * 259 + row) * 129 + c];
}

__global__ void build_csr(const int* __restrict__ ei, const float* __restrict__ pos,
                          int* __restrict__ cnt, int2* __restrict__ csr) {
  int e = blockIdx.x * 256 + threadIdx.x;
  if (e >= N_EDGES) return;
  int s = ei[e];
  int d = ei[N_EDGES + e];
  float dx = pos[s * 3 + 0] - pos[d * 3 + 0];
  float dy = pos[s * 3 + 1] - pos[d * 3 + 1];
  float dz = pos[s * 3 + 2] - pos[d * 3 + 2];
  float ea = sqrtf(dx * dx + dy * dy + dz * dz);
  int p = atomicAdd(&cnt[d], 1);
  if (p < CAP) csr[d * CAP + p] = make_int2(s, __float_as_int(ea));
}

// graph start offsets from sorted batch; goff[256]=N sentinel
__global__ void offsets_k(const int* __restrict__ batch, int* __restrict__ goff) {
  int n = blockIdx.x * 256 + threadIdx.x;
  if (n > N_NODES) return;
  int b = (n < N_NODES) ? batch[n] : NUM_GRAPHS;
  int bp = (n > 0) ? batch[n - 1] : -1;
  for (int g = bp + 1; g <= b; ++g) goff[g] = n;
}

// 32 rows x (4 groups x 144 cols) per block; wave w = group w.
// Outputs pre-scaled by SCL for the exp2-domain edge kernel.
// Pfs u16 layout per src row (256 u16): [f(2c),f(2c+1),s(2c),s(2c+1)] at c*4.
__global__ __launch_bounds__(256) void gemm_mfma(
    const unsigned* __restrict__ xbu, const float* __restrict__ xf,
    const uint4* __restrict__ Bp, const float* __restrict__ W128,
    const float* __restrict__ bfL, const float* __restrict__ bsL,
    float* __restrict__ Pd, unsigned short* __restrict__ Pfs,
    unsigned short* __restrict__ Psf128, unsigned short* __restrict__ Pss128,
    int layer) {
  __shared__ short smA[32 * 136];  // row stride 136 shorts (conflict-free b128)
  int n0 = blockIdx.x * 32;
  int tid = threadIdx.x;
  for (int ch = tid; ch < 512; ch += 256) {
    int row = ch >> 4, cq = ch & 15;
    *(uint4*)(&smA[row * 136 + cq * 8]) =
        *(const uint4*)(xbu + (size_t)(n0 + row) * 64 + cq * 4);
  }
  __syncthreads();
  int g = tid >> 6;
  int l = tid & 63;
  int q = l >> 4, c16 = l & 15;
  const short8* Bp8 = (const short8*)Bp;
  int bbase = (layer * 4 + g) * 9 * 4;
  f32x4 acc[2][9];
#pragma unroll
  for (int rt = 0; rt < 2; ++rt)
#pragma unroll
    for (int ct = 0; ct < 9; ++ct) acc[rt][ct] = (f32x4){0.f, 0.f, 0.f, 0.f};
#pragma unroll
  for (int ks = 0; ks < 4; ++ks) {
    short8 a0 = *(const short8*)(&smA[c16 * 136 + (ks * 4 + q) * 8]);
    short8 a1 = *(const short8*)(&smA[(16 + c16) * 136 + (ks * 4 + q) * 8]);
#pragma unroll
    for (int ct = 0; ct < 9; ++ct) {
      short8 b = Bp8[(size_t)(bbase + ct * 4 + ks) * 64 + l];
      acc[0][ct] = __builtin_amdgcn_mfma_f32_16x16x32_bf16(a0, b, acc[0][ct], 0, 0, 0);
      acc[1][ct] = __builtin_amdgcn_mfma_f32_16x16x32_bf16(a1, b, acc[1][ct], 0, 0, 0);
    }
  }
  const float* W1g = W128 + (layer * 4 + g) * 129;
  float x128[2][4];
#pragma unroll
  for (int rt = 0; rt < 2; ++rt)
#pragma unroll
    for (int r = 0; r < 4; ++r)
      x128[rt][r] = xf[(size_t)(n0 + rt * 16 + q * 4 + r) * XS + 128];
#pragma unroll
  for (int ct = 0; ct < 9; ++ct) {
    int col = ct * 16 + c16;
    float w1 = (col <= 128) ? W1g[col] : 0.0f;
    float bias = 0.0f;
    if (g == 0 && col <= 128) bias = bfL[col];
    if (g == 2 && col <= 128) bias = bsL[col];
#pragma unroll
    for (int rt = 0; rt < 2; ++rt) {
#pragma unroll
      for (int r = 0; r < 4; ++r) {
        int row = n0 + rt * 16 + q * 4 + r;
        float v = SCL * (acc[rt][ct][r] + x128[rt][r] * w1 + bias);
        if (g == 0) {
          if (col <= 128) Pd[(size_t)row * PDS + col] = v;
        } else if (g == 2) {
          if (col <= 128) Pd[(size_t)row * PDS + 132 + col] = v;
        } else if (g == 1) {
          if (col < 128)
            Pfs[(size_t)row * 256 + ((col >> 1) << 2) + (col & 1)] = (unsigned short)f2bf(v);
          else if (col == 128)
            Psf128[row] = (unsigned short)f2bf(v);
        } else {
          if (col < 128)
            Pfs[(size_t)row * 256 + ((col >> 1) << 2) + 2 + (col & 1)] = (unsigned short)f2bf(v);
          else if (col == 128)
            Pss128[row] = (unsigned short)f2bf(v);
        }
      }
    }
  }
}

// msg = sigmoid(gf)*softplus(gs) computed in exp2 domain: inputs pre-scaled by SCL.
#define EDGE_CH(gfp, gsp, acc)                                          \
  {                                                                     \
    float r_ = fast_rcp(1.0f + EX2(gfp));                               \
    float t_ = LG2(1.0f + EX2(-fabsf(gsp))) - fminf(gsp, 0.0f);         \
    acc = fmaf(r_ * t_, C693, acc);                                     \
  }

// one wave per dst node; lane = channels {2l, 2l+1}; residual update in place.
__global__ __launch_bounds__(256) void edge_agg(
    const float* __restrict__ Pd, const unsigned short* __restrict__ Pfs,
    const unsigned short* __restrict__ Psf128, const unsigned short* __restrict__ Pss128,
    float* __restrict__ xf, unsigned* __restrict__ xbu, const int* __restrict__ cnt,
    const int2* __restrict__ csr, const float* __restrict__ WfL,
    const float* __restrict__ WsL) {
  int lane = threadIdx.x & 63;
  int n = blockIdx.x * 4 + (threadIdx.x >> 6);
  if (n >= N_NODES) return;
  int nu = __builtin_amdgcn_readfirstlane(n);  // wave-uniform -> scalar pipe
  const float* wfl = WfL + 258 * 129;
  const float* wsl = WsL + 258 * 129;
  const float* Pn = Pd + (size_t)nu * PDS;
  int ce = 2 * lane;
  float2 bfp = *(const float2*)(Pn + ce);        // pre-scaled, bias folded
  float2 bsp = *(const float2*)(Pn + 132 + ce);
  float2 wf0 = *(const float2*)(wfl + ce);
  float2 ws0 = *(const float2*)(wsl + ce);
  float2 wfp = make_float2(SCL * wf0.x, SCL * wf0.y);
  float2 wsp = make_float2(SCL * ws0.x, SCL * ws0.y);
  float bf2 = Pn[128], bs2 = Pn[260];
  float wf2 = SCL * wfl[128], ws2 = SCL * wsl[128];
  int m = cnt[nu];
  if (m > CAP) m = CAP;
  const int2* cb = csr + (size_t)nu * CAP;
  const uint2* Pf2 = (const uint2*)Pfs;
  float a0 = 0.f, a1 = 0.f;
  int e = 0;
  for (; e + 1 < m; e += 2) {
    int2 sa = cb[e];
    int2 sb = cb[e + 1];
    uint2 pa = Pf2[(size_t)sa.x * 64 + lane];
    uint2 pb = Pf2[(size_t)sb.x * 64 + lane];
    float eaa = __int_as_float(sa.y);
    float eab = __int_as_float(sb.y);
    {
      float gf0 = fmaf(eaa, wfp.x, bfp.x + u2f(pa.x << 16));
      float gs0 = fmaf(eaa, wsp.x, bsp.x + u2f(pa.y << 16));
      float gf1 = fmaf(eaa, wfp.y, bfp.y + u2f(pa.x & 0xffff0000u));
      float gs1 = fmaf(eaa, wsp.y, bsp.y + u2f(pa.y & 0xffff0000u));
      EDGE_CH(gf0, gs0, a0);
      EDGE_CH(gf1, gs1, a1);
    }
    {
      float gf0 = fmaf(eab, wfp.x, bfp.x + u2f(pb.x << 16));
      float gs0 = fmaf(eab, wsp.x, bsp.x + u2f(pb.y << 16));
      float gf1 = fmaf(eab, wfp.y, bfp.y + u2f(pb.x & 0xffff0000u));
      float gs1 = fmaf(eab, wsp.y, bsp.y + u2f(pb.y & 0xffff0000u));
      EDGE_CH(gf0, gs0, a0);
      EDGE_CH(gf1, gs1, a1);
    }
  }
  if (e < m) {
    int2 sa = cb[e];
    uint2 pa = Pf2[(size_t)sa.x * 64 + lane];
    float eaa = __int_as_float(sa.y);
    float gf0 = fmaf(eaa, wfp.x, bfp.x + u2f(pa.x << 16));
    float gs0 = fmaf(eaa, wsp.x, bsp.x + u2f(pa.y << 16));
    float gf1 = fmaf(eaa, wfp.y, bfp.y + u2f(pa.x & 0xffff0000u));
    float gs1 = fmaf(eaa, wsp.y, bsp.y + u2f(pa.y & 0xffff0000u));
    EDGE_CH(gf0, gs0, a0);
    EDGE_CH(gf1, gs1, a1);
  }
  // channel 128: lanes parallel over edges (deg <= 64), then butterfly reduce
  float v2 = 0.f;
  if (lane < m) {
    int2 se = cb[lane];
    float ea = __int_as_float(se.y);
    float f2 = u2f(((unsigned)Psf128[se.x]) << 16);
    float s2 = u2f(((unsigned)Pss128[se.x]) << 16);
    float gf2 = fmaf(ea, wf2, bf2 + f2);
    float gs2 = fmaf(ea, ws2, bs2 + s2);
    float r_ = fast_rcp(1.0f + EX2(gf2));
    float t_ = LG2(1.0f + EX2(-fabsf(gs2))) - fminf(gs2, 0.0f);
    v2 = C693 * r_ * t_;
  }
#pragma unroll
  for (int off = 32; off; off >>= 1) v2 += __shfl_down(v2, off, 64);
  size_t xo = (size_t)nu * XS;
  float2 xv = *(const float2*)(xf + xo + ce);
  float2 res = make_float2(xv.x + a0, xv.y + a1);
  *(float2*)(xf + xo + ce) = res;
  xbu[(size_t)nu * 64 + lane] = f2bf(res.x) | (f2bf(res.y) << 16);
  if (lane == 0) xf[xo + 128] += v2;
}

// one block per graph over its contiguous node range; writes the MEAN directly
__global__ void pool2(const float* __restrict__ xf, const int* __restrict__ goff,
                      float* __restrict__ gsum) {
  int gph = blockIdx.x;
  int t = threadIdx.x;
  if (t >= 129) return;
  int s = goff[gph], e = goff[gph + 1];
  float acc = 0.f;
  for (int n = s; n < e; ++n) acc += xf[(size_t)n * XS + t];
  gsum[gph * XS + t] = acc * fast_rcp(fmaxf((float)(e - s), 1.0f));
}

__global__ void fc(const float* __restrict__ gin, const float* __restrict__ W,
                   const float* __restrict__ b, float* __restrict__ gout) {
  __shared__ float row[132];
  int i = blockIdx.x;
  int t = threadIdx.x;
  if (t < 129) row[t] = gin[i * XS + t];
  __syncthreads();
  if (t < 129) {
    float s = b[t];
#pragma unroll 4
    for (int k = 0; k < 129; ++k) s += row[k] * W[k * 129 + t];
    gout[i * XS + t] = s;
  }
}

__global__ void outk(const float* __restrict__ gin, const float* __restrict__ Wout,
                     const float* __restrict__ bout, float* __restrict__ out) {
  int i = threadIdx.x;  // 256 graphs
  float s = bout[0];
#pragma unroll 4
  for (int k = 0; k < 129; ++k) s += gin[i * XS + k] * Wout[k];
  out[i] = s;
}

extern "C" void kernel_launch(void* const* d_in, const int* in_sizes, int n_in,
                              void* d_out, int out_size, void* d_ws, size_t ws_size,
                              hipStream_t stream) {
  const int* atoms = (const int*)d_in[0];
  const float* pos = (const float*)d_in[1];
  const int* ei = (const int*)d_in[2];
  const int* batch = (const int*)d_in[3];
  const float* emb = (const float*)d_in[4];
  const float* Wf = (const float*)d_in[5];
  const float* bfp = (const float*)d_in[6];
  const float* Ws = (const float*)d_in[7];
  const float* bsp = (const float*)d_in[8];
  const float* Wfc = (const float*)d_in[9];
  const float* bfc = (const float*)d_in[10];
  const float* Wout = (const float*)d_in[11];
  const float* bout = (const float*)d_in[12];
  float* outp = (float*)d_out;

  // workspace layout (16B-aligned head)
  uint4* Bp = (uint4*)d_ws;                                   // 46080 uint4
  float* xf = (float*)(Bp + 46080);                           // NPADROWS*132
  float* Pd = xf + (size_t)NPADROWS * XS;                     // NPADROWS*264
  unsigned* xbu = (unsigned*)(Pd + (size_t)NPADROWS * PDS);   // NPADROWS*64
  unsigned short* Pfs = (unsigned short*)(xbu + (size_t)NPADROWS * 64);  // NPADROWS*256 u16
  float* W128 = (float*)(Pfs + (size_t)NPADROWS * 256);       // 2580
  float* gsum = W128 + 2580;                                  // 256*132
  float* gA = gsum + 256 * XS;
  float* gB = gA + 256 * XS;
  int* goff = (int*)(gB + 256 * XS);                          // 258 (padded)
  int* cnt = goff + 258;                                      // N_NODES
  int2* csr = (int2*)(cnt + N_NODES);                         // N_NODES*CAP
  unsigned short* Psf128 = (unsigned short*)(csr + (size_t)N_NODES * CAP);
  unsigned short* Pss128 = Psf128 + NPADROWS;

  hipMemsetAsync(cnt, 0, N_NODES * sizeof(int), stream);

  init_x<<<N_NODES, 64, 0, stream>>>(atoms, pos, emb, xf, xbu);
  prep_b<<<(5 * 4 * 9 * 4 * 64 + 255) / 256, 256, 0, stream>>>(Wf, Ws, Bp);
  prep_w128<<<(5 * 4 * 129 + 255) / 256, 256, 0, stream>>>(Wf, Ws, W128);
  build_csr<<<(N_EDGES + 255) / 256, 256, 0, stream>>>(ei, pos, cnt, csr);
  offsets_k<<<(N_NODES + 256) / 256, 256, 0, stream>>>(batch, goff);

  for (int l = 0; l < 5; ++l) {
    gemm_mfma<<<NPADROWS / 32, 256, 0, stream>>>(xbu, xf, Bp, W128, bfp + l * 129,
                                                 bsp + l * 129, Pd, Pfs, Psf128,
                                                 Pss128, l);
    edge_agg<<<(N_NODES + 3) / 4, 256, 0, stream>>>(Pd, Pfs, Psf128, Pss128, xf, xbu,
                                                    cnt, csr,
                                                    Wf + (size_t)l * 259 * 129,
                                                    Ws + (size_t)l * 259 * 129);
  }

  pool2<<<NUM_GRAPHS, 192, 0, stream>>>(xf, goff, gsum);
  fc<<<NUM_GRAPHS, 192, 0, stream>>>(gsum, Wfc, bfc, gA);
  fc<<<NUM_GRAPHS, 192, 0, stream>>>(gA, Wfc + 129 * 129, bfc + 129, gB);
  fc<<<NUM_GRAPHS, 192, 0, stream>>>(gB, Wfc + 2 * 129 * 129, bfc + 2 * 129, gA);
  outk<<<1, 256, 0, stream>>>(gA, Wout, bout, outp);
}

// Round 6
// 785.808 us; speedup vs baseline: 2.3090x; 1.1092x over previous
//
#include <hip/hip_runtime.h>
#include <math.h>

#define N_NODES 50000
#define N_EDGES 800000
#define NUM_GRAPHS 256
#define NPADROWS 50048   // 1564*32
#define CAP 64           // CSR capacity per node (max observed degree ~35)
#define XS 132           // xf row stride (floats); [0..127]=emb ch, [128]=z
#define SCLN -1.44269504088896f  // -log2(e): f-side scale, exp2(SCLN*x)=exp(-x)
#define SCLP 1.44269504088896f   // +log2(e): s-side scale
#define C693 0.69314718056f

typedef __attribute__((ext_vector_type(8))) short short8;
typedef __attribute__((ext_vector_type(4))) float f32x4;
typedef __attribute__((ext_vector_type(2))) float f32x2;

__device__ __forceinline__ float fast_rcp(float x) {
#if __has_builtin(__builtin_amdgcn_rcpf)
  return __builtin_amdgcn_rcpf(x);
#else
  return 1.0f / x;
#endif
}
__device__ __forceinline__ float EX2(float x) {
#if __has_builtin(__builtin_amdgcn_exp2f)
  return __builtin_amdgcn_exp2f(x);
#else
  return exp2f(x);
#endif
}
__device__ __forceinline__ float LG2(float x) {
#if __has_builtin(__builtin_amdgcn_logf)
  return __builtin_amdgcn_logf(x);  // log2
#else
  return log2f(x);
#endif
}
__device__ __forceinline__ unsigned f2bf(float x) {
  unsigned u = __float_as_uint(x);
  return (u + 0x7fffu + ((u >> 16) & 1u)) >> 16;
}
__device__ __forceinline__ float u2f(unsigned u) { return __uint_as_float(u); }
__device__ __forceinline__ f32x2 mk2(float a, float b) {
  f32x2 r; r.x = a; r.y = b; return r;
}
// unpack u32 holding (lo u16 -> ch0 bf16, hi u16 -> ch1 bf16) to f32x2
__device__ __forceinline__ f32x2 unp(unsigned u) {
  return mk2(u2f(u << 16), u2f(u & 0xffff0000u));
}

// xf[n][0:128]=emb, xf[n][128]=pos.z ; xb packed bf16 pairs (64 u32/row)
__global__ void init_x(const int* __restrict__ atoms, const float* __restrict__ pos,
                       const float* __restrict__ emb, float* __restrict__ xf,
                       unsigned* __restrict__ xbu) {
  int n = blockIdx.x;  // 64 threads
  int t = threadIdx.x;
  int a = atoms[n];
  float2 e = *(const float2*)(emb + (size_t)a * 128 + 2 * t);
  xf[(size_t)n * XS + 2 * t] = e.x;
  xf[(size_t)n * XS + 2 * t + 1] = e.y;
  xbu[(size_t)n * 64 + t] = f2bf(e.x) | (f2bf(e.y) << 16);
  if (t == 0) xf[(size_t)n * XS + 128] = pos[n * 3 + 2];
}

// pos padded to float4 for single-line gathers
__global__ void prep_pos(const float* __restrict__ pos, float4* __restrict__ pos4) {
  int n = blockIdx.x * 256 + threadIdx.x;
  if (n >= N_NODES) return;
  pos4[n] = make_float4(pos[3 * n], pos[3 * n + 1], pos[3 * n + 2], 0.f);
}

// B packed in exact MFMA B-fragment order:
// Bp[((l*4+g)*9+ct)*4+ks][lane] = 8 bf16: B[k=ks*32+(lane>>4)*8+j][col=ct*16+(lane&15)]
__global__ void prep_b(const float* __restrict__ Wf, const float* __restrict__ Ws,
                       uint4* __restrict__ Bp) {
  int idx = blockIdx.x * 256 + threadIdx.x;
  if (idx >= 5 * 4 * 9 * 4 * 64) return;
  int lane = idx & 63;
  int t = idx >> 6;
  int ks = t & 3; t >>= 2;
  int ct = t % 9; t /= 9;
  int g = t & 3;
  int l = t >> 2;
  const float* W = (g >= 2) ? Ws : Wf;
  int col = ct * 16 + (lane & 15);
  int kb = ks * 32 + (lane >> 4) * 8;
  unsigned u[4];
#pragma unroll
  for (int p = 0; p < 4; ++p) {
    unsigned lo = 0, hi = 0;
    if (col < 129) {
      int k0 = kb + 2 * p, k1 = k0 + 1;
      int r0 = (g & 1) ? 129 + k0 : k0;
      int r1 = (g & 1) ? 129 + k1 : k1;
      lo = f2bf(W[(size_t)(l * 259 + r0) * 129 + col]);
      hi = f2bf(W[(size_t)(l * 259 + r1) * 129 + col]);
    }
    u[p] = lo | (hi << 16);
  }
  Bp[idx] = make_uint4(u[0], u[1], u[2], u[3]);
}

// rank-1 row: W128[(l*4+g)*129 + c] = W[k=128][c] (dst) or W[k=257][c] (src)
__global__ void prep_w128(const float* __restrict__ Wf, const float* __restrict__ Ws,
                          float* __restrict__ W128) {
  int idx = blockIdx.x * 256 + threadIdx.x;
  if (idx >= 5 * 4 * 129) return;
  int c = idx % 129;
  int t = idx / 129;
  int g = t & 3;
  int l = t >> 2;
  const float* W = (g >= 2) ? Ws : Wf;
  int row = (g & 1) ? 257 : 128;
  W128[(l * 4 + g) * 129 + c] = W[(size_t)(l * 259 + row) * 129 + c];
}

__global__ void build_csr(const int* __restrict__ ei, const float4* __restrict__ pos4,
                          int* __restrict__ cnt, int2* __restrict__ csr) {
  int e = blockIdx.x * 256 + threadIdx.x;
  if (e >= N_EDGES) return;
  int s = ei[e];
  int d = ei[N_EDGES + e];
  float4 ps = pos4[s];
  float4 pd = pos4[d];
  float dx = ps.x - pd.x, dy = ps.y - pd.y, dz = ps.z - pd.z;
  float ea = sqrtf(dx * dx + dy * dy + dz * dz);
  int p = atomicAdd(&cnt[d], 1);
  if (p < CAP) csr[d * CAP + p] = make_int2(s, __float_as_int(ea));
}

// graph start offsets from sorted batch; goff[256]=N sentinel
__global__ void offsets_k(const int* __restrict__ batch, int* __restrict__ goff) {
  int n = blockIdx.x * 256 + threadIdx.x;
  if (n > N_NODES) return;
  int b = (n < N_NODES) ? batch[n] : NUM_GRAPHS;
  int bp = (n > 0) ? batch[n - 1] : -1;
  for (int g = bp + 1; g <= b; ++g) goff[g] = n;
}

// 32 rows x (4 groups x 144 cols) per block; wave w = group w.
// f-side (g0,g1) scaled by SCLN; s-side (g2,g3) by SCLP.
// u16 row layout (256 u16): [f(2c),f(2c+1),s(2c),s(2c+1)] at c*4 — Pdh for dst, Pfs for src.
__global__ __launch_bounds__(256) void gemm_mfma(
    const unsigned* __restrict__ xbu, const float* __restrict__ xf,
    const uint4* __restrict__ Bp, const float* __restrict__ W128,
    const float* __restrict__ bfL, const float* __restrict__ bsL,
    unsigned short* __restrict__ Pdh, unsigned short* __restrict__ Pfs,
    unsigned short* __restrict__ Pd128,  // stride 2: [2n]=f, [2n+1]=s
    unsigned short* __restrict__ Psf128, unsigned short* __restrict__ Pss128,
    int layer) {
  __shared__ short smA[32 * 136];  // row stride 136 shorts (conflict-free b128)
  int n0 = blockIdx.x * 32;
  int tid = threadIdx.x;
  for (int ch = tid; ch < 512; ch += 256) {
    int row = ch >> 4, cq = ch & 15;
    *(uint4*)(&smA[row * 136 + cq * 8]) =
        *(const uint4*)(xbu + (size_t)(n0 + row) * 64 + cq * 4);
  }
  __syncthreads();
  int g = tid >> 6;
  int l = tid & 63;
  int q = l >> 4, c16 = l & 15;
  const short8* Bp8 = (const short8*)Bp;
  int bbase = (layer * 4 + g) * 9 * 4;
  f32x4 acc[2][9];
#pragma unroll
  for (int rt = 0; rt < 2; ++rt)
#pragma unroll
    for (int ct = 0; ct < 9; ++ct) acc[rt][ct] = (f32x4){0.f, 0.f, 0.f, 0.f};
#pragma unroll
  for (int ks = 0; ks < 4; ++ks) {
    short8 a0 = *(const short8*)(&smA[c16 * 136 + (ks * 4 + q) * 8]);
    short8 a1 = *(const short8*)(&smA[(16 + c16) * 136 + (ks * 4 + q) * 8]);
#pragma unroll
    for (int ct = 0; ct < 9; ++ct) {
      short8 b = Bp8[(size_t)(bbase + ct * 4 + ks) * 64 + l];
      acc[0][ct] = __builtin_amdgcn_mfma_f32_16x16x32_bf16(a0, b, acc[0][ct], 0, 0, 0);
      acc[1][ct] = __builtin_amdgcn_mfma_f32_16x16x32_bf16(a1, b, acc[1][ct], 0, 0, 0);
    }
  }
  const float* W1g = W128 + (layer * 4 + g) * 129;
  float x128[2][4];
#pragma unroll
  for (int rt = 0; rt < 2; ++rt)
#pragma unroll
    for (int r = 0; r < 4; ++r)
      x128[rt][r] = xf[(size_t)(n0 + rt * 16 + q * 4 + r) * XS + 128];
  float scale = (g < 2) ? SCLN : SCLP;
  unsigned short* dstp = (g & 1) ? Pfs : Pdh;
  int soff = (g >= 2) ? 2 : 0;
#pragma unroll
  for (int ct = 0; ct < 9; ++ct) {
    int col = ct * 16 + c16;
    float w1 = (col <= 128) ? W1g[col] : 0.0f;
    float bias = 0.0f;
    if (g == 0 && col <= 128) bias = bfL[col];
    if (g == 2 && col <= 128) bias = bsL[col];
#pragma unroll
    for (int rt = 0; rt < 2; ++rt) {
#pragma unroll
      for (int r = 0; r < 4; ++r) {
        int row = n0 + rt * 16 + q * 4 + r;
        float v = scale * (acc[rt][ct][r] + x128[rt][r] * w1 + bias);
        unsigned short bv = (unsigned short)f2bf(v);
        if (col < 128) {
          dstp[(size_t)row * 256 + ((col >> 1) << 2) + soff + (col & 1)] = bv;
        } else if (col == 128) {
          if (g == 0) Pd128[2 * (size_t)row] = bv;
          else if (g == 2) Pd128[2 * (size_t)row + 1] = bv;
          else if (g == 1) Psf128[row] = bv;
          else Pss128[row] = bv;
        }
      }
    }
  }
}

// msg = sigmoid * softplus, exp2 domain, f32x2-packed.
// gf pre-scaled by -log2e: sigm = rcp(1+exp2(gf)); exp2 overflow -> inf -> rcp=0 (correct).
// gs pre-scaled by +log2e: softplus_log2 = max(gs,0) + log2(1+exp2(-|gs|))  [STABLE:
// exp2 arg always <= 0; linear regime preserved for large gs — R5's clamp broke this].
#define EDGE2(pa, eav, acc2)                                              \
  {                                                                       \
    f32x2 gf = __builtin_elementwise_fma(eav, wfp2, bfp2 + unp(pa.x));    \
    f32x2 gs = __builtin_elementwise_fma(eav, wsp2, bsp2 + unp(pa.y));    \
    f32x2 den = mk2(EX2(gf.x), EX2(gf.y)) + 1.0f;                         \
    f32x2 lg = mk2(LG2(1.0f + EX2(-fabsf(gs.x))),                         \
                   LG2(1.0f + EX2(-fabsf(gs.y))));                        \
    f32x2 sp = lg + __builtin_elementwise_max(gs, (f32x2)0.0f);           \
    f32x2 rt = mk2(fast_rcp(den.x), fast_rcp(den.y)) * sp;                \
    acc2 = __builtin_elementwise_fma(rt, (f32x2)C693, acc2);              \
  }

// one wave per dst node; lane = channels {2l, 2l+1}; residual update in place.
__global__ __launch_bounds__(256) void edge_agg(
    const unsigned short* __restrict__ Pdh, const unsigned short* __restrict__ Pfs,
    const unsigned short* __restrict__ Pd128, const unsigned short* __restrict__ Psf128,
    const unsigned short* __restrict__ Pss128, float* __restrict__ xf,
    unsigned* __restrict__ xbu, const int* __restrict__ cnt,
    const int2* __restrict__ csr, const float* __restrict__ WfL,
    const float* __restrict__ WsL) {
  int lane = threadIdx.x & 63;
  int n = blockIdx.x * 4 + (threadIdx.x >> 6);
  if (n >= N_NODES) return;
  int nu = __builtin_amdgcn_readfirstlane(n);  // wave-uniform -> scalar pipe
  const float* wfl = WfL + 258 * 129;
  const float* wsl = WsL + 258 * 129;
  int ce = 2 * lane;
  uint2 pdv = *(const uint2*)(Pdh + (size_t)nu * 256 + 4 * lane);
  f32x2 bfp2 = unp(pdv.x);  // pre-scaled, bias folded (bf16)
  f32x2 bsp2 = unp(pdv.y);
  float2 wf0 = *(const float2*)(wfl + ce);
  float2 ws0 = *(const float2*)(wsl + ce);
  f32x2 wfp2 = mk2(SCLN * wf0.x, SCLN * wf0.y);
  f32x2 wsp2 = mk2(SCLP * ws0.x, SCLP * ws0.y);
  unsigned pd1 = *(const unsigned*)(Pd128 + 2 * (size_t)nu);
  float bfc8 = u2f(pd1 << 16), bsc8 = u2f(pd1 & 0xffff0000u);
  float wfc8 = SCLN * wfl[128], wsc8 = SCLP * wsl[128];
  int m = cnt[nu];
  if (m > CAP) m = CAP;
  const int2* cb = csr + (size_t)nu * CAP;
  const uint2* Pf2 = (const uint2*)Pfs;
  f32x2 acc2 = (f32x2)0.0f;
  int e = 0;
  for (; e + 1 < m; e += 2) {
    int2 sa = cb[e];
    int2 sb = cb[e + 1];
    uint2 pa = Pf2[(size_t)sa.x * 64 + lane];
    uint2 pb = Pf2[(size_t)sb.x * 64 + lane];
    f32x2 eava = (f32x2)__int_as_float(sa.y);
    f32x2 eavb = (f32x2)__int_as_float(sb.y);
    EDGE2(pa, eava, acc2);
    EDGE2(pb, eavb, acc2);
  }
  if (e < m) {
    int2 sa = cb[e];
    uint2 pa = Pf2[(size_t)sa.x * 64 + lane];
    f32x2 eava = (f32x2)__int_as_float(sa.y);
    EDGE2(pa, eava, acc2);
  }
  // channel 128: lanes parallel over edges (deg <= 64), then butterfly reduce
  float v2 = 0.f;
  if (lane < m) {
    int2 se = cb[lane];
    float ea = __int_as_float(se.y);
    float f2 = u2f(((unsigned)Psf128[se.x]) << 16);
    float s2 = u2f(((unsigned)Pss128[se.x]) << 16);
    float gf2 = fmaf(ea, wfc8, bfc8 + f2);
    float gs2 = fmaf(ea, wsc8, bsc8 + s2);
    float sp2 = LG2(1.0f + EX2(-fabsf(gs2))) + fmaxf(gs2, 0.0f);
    v2 = C693 * fast_rcp(1.0f + EX2(gf2)) * sp2;
  }
#pragma unroll
  for (int off = 32; off; off >>= 1) v2 += __shfl_down(v2, off, 64);
  size_t xo = (size_t)nu * XS;
  float2 xv = *(const float2*)(xf + xo + ce);
  float2 res = make_float2(xv.x + acc2.x, xv.y + acc2.y);
  *(float2*)(xf + xo + ce) = res;
  xbu[(size_t)nu * 64 + lane] = f2bf(res.x) | (f2bf(res.y) << 16);
  if (lane == 0) xf[xo + 128] += v2;
}

// 4 blocks per graph, partial sums + light atomics; gsum pre-zeroed
__global__ void pool2(const float* __restrict__ xf, const int* __restrict__ goff,
                      float* __restrict__ gsum) {
  int gph = blockIdx.x >> 2;
  int q = blockIdx.x & 3;
  int t = threadIdx.x;
  if (t >= 129) return;
  int s = goff[gph], e = goff[gph + 1];
  int len = e - s;
  int chunk = (len + 3) >> 2;
  int a = s + q * chunk;
  int b = a + chunk; if (b > e) b = e;
  if (a >= b) return;
  float acc = 0.f;
  for (int n = a; n < b; ++n) acc += xf[(size_t)n * XS + t];
  atomicAdd(&gsum[gph * XS + t], acc);
}

// fused: mean-divide + fc1 + fc2 + fc3 + out. one block per graph, 192 thr.
__global__ void fcout(const float* __restrict__ gsum, const int* __restrict__ goff,
                      const float* __restrict__ Wfc, const float* __restrict__ bfc,
                      const float* __restrict__ Wout, const float* __restrict__ bout,
                      float* __restrict__ out) {
  __shared__ float buf[2][132];
  __shared__ float red[3];
  int i = blockIdx.x;
  int t = threadIdx.x;
  int len = goff[i + 1] - goff[i];
  float inv = fast_rcp(fmaxf((float)len, 1.0f));
  if (t < 129) buf[0][t] = gsum[i * XS + t] * inv;
  __syncthreads();
  int cur = 0;
#pragma unroll
  for (int l = 0; l < 3; ++l) {
    float s = 0.f;
    if (t < 129) {
      s = bfc[l * 129 + t];
      const float* W = Wfc + (size_t)l * 129 * 129;
#pragma unroll 4
      for (int k = 0; k < 129; ++k) s += buf[cur][k] * W[k * 129 + t];
    }
    __syncthreads();
    if (t < 129) buf[1 - cur][t] = s;
    cur = 1 - cur;
    __syncthreads();
  }
  float p = (t < 129) ? buf[cur][t] * Wout[t] : 0.f;
#pragma unroll
  for (int off = 32; off; off >>= 1) p += __shfl_down(p, off, 64);
  if ((t & 63) == 0) red[t >> 6] = p;
  __syncthreads();
  if (t == 0) out[i] = red[0] + red[1] + red[2] + bout[0];
}

extern "C" void kernel_launch(void* const* d_in, const int* in_sizes, int n_in,
                              void* d_out, int out_size, void* d_ws, size_t ws_size,
                              hipStream_t stream) {
  const int* atoms = (const int*)d_in[0];
  const float* pos = (const float*)d_in[1];
  const int* ei = (const int*)d_in[2];
  const int* batch = (const int*)d_in[3];
  const float* emb = (const float*)d_in[4];
  const float* Wf = (const float*)d_in[5];
  const float* bfp = (const float*)d_in[6];
  const float* Ws = (const float*)d_in[7];
  const float* bsp = (const float*)d_in[8];
  const float* Wfc = (const float*)d_in[9];
  const float* bfc = (const float*)d_in[10];
  const float* Wout = (const float*)d_in[11];
  const float* bout = (const float*)d_in[12];
  float* outp = (float*)d_out;

  // workspace layout (16B-aligned head)
  uint4* Bp = (uint4*)d_ws;                                   // 46080 uint4
  float* xf = (float*)(Bp + 46080);                           // NPADROWS*132 f32
  unsigned* xbu = (unsigned*)(xf + (size_t)NPADROWS * XS);    // NPADROWS*64 u32
  unsigned short* Pdh = (unsigned short*)(xbu + (size_t)NPADROWS * 64);  // NPADROWS*256
  unsigned short* Pfs = Pdh + (size_t)NPADROWS * 256;         // NPADROWS*256
  float4* pos4 = (float4*)(Pfs + (size_t)NPADROWS * 256);     // N_NODES float4
  float* W128 = (float*)(pos4 + N_NODES);                     // 2580
  float* gsum = W128 + 2580;                                  // 256*132
  int* goff = (int*)(gsum + 256 * XS);                        // 258 (padded)
  int* cnt = goff + 258;                                      // N_NODES
  int2* csr = (int2*)(cnt + N_NODES);                         // N_NODES*CAP
  unsigned short* Pd128 = (unsigned short*)(csr + (size_t)N_NODES * CAP);  // 2*NPADROWS
  unsigned short* Psf128 = Pd128 + 2 * NPADROWS;              // NPADROWS
  unsigned short* Pss128 = Psf128 + NPADROWS;                 // NPADROWS

  hipMemsetAsync(cnt, 0, N_NODES * sizeof(int), stream);
  hipMemsetAsync(gsum, 0, 256 * XS * sizeof(float), stream);

  init_x<<<N_NODES, 64, 0, stream>>>(atoms, pos, emb, xf, xbu);
  prep_pos<<<(N_NODES + 255) / 256, 256, 0, stream>>>(pos, pos4);
  prep_b<<<(5 * 4 * 9 * 4 * 64 + 255) / 256, 256, 0, stream>>>(Wf, Ws, Bp);
  prep_w128<<<(5 * 4 * 129 + 255) / 256, 256, 0, stream>>>(Wf, Ws, W128);
  build_csr<<<(N_EDGES + 255) / 256, 256, 0, stream>>>(ei, pos4, cnt, csr);
  offsets_k<<<(N_NODES + 256) / 256, 256, 0, stream>>>(batch, goff);

  for (int l = 0; l < 5; ++l) {
    gemm_mfma<<<NPADROWS / 32, 256, 0, stream>>>(xbu, xf, Bp, W128, bfp + l * 129,
                                                 bsp + l * 129, Pdh, Pfs, Pd128,
                                                 Psf128, Pss128, l);
    edge_agg<<<(N_NODES + 3) / 4, 256, 0, stream>>>(Pdh, Pfs, Pd128, Psf128, Pss128,
                                                    xf, xbu, cnt, csr,
                                                    Wf + (size_t)l * 259 * 129,
                                                    Ws + (size_t)l * 259 * 129);
  }

  pool2<<<NUM_GRAPHS * 4, 192, 0, stream>>>(xf, goff, gsum);
  fcout<<<NUM_GRAPHS, 192, 0, stream>>>(gsum, goff, Wfc, bfc, Wout, bout, outp);
}

// Round 7
// 757.562 us; speedup vs baseline: 2.3951x; 1.0373x over previous
//
#include <hip/hip_runtime.h>
#include <math.h>

#define N_NODES 50000
#define N_EDGES 800000
#define NUM_GRAPHS 256
#define NPADROWS 50048   // 1564*32
#define CAP 64           // CSR capacity per node (max observed degree ~35)
#define XS 132           // xf row stride (floats); [0..127]=emb ch, [128]=z
#define SCLN -1.44269504088896f  // -log2(e): f-side scale, exp2(SCLN*x)=exp(-x)
#define SCLP 1.44269504088896f   // +log2(e): s-side scale
#define C693 0.69314718056f

typedef __attribute__((ext_vector_type(8))) short short8;
typedef __attribute__((ext_vector_type(4))) float f32x4;
typedef __attribute__((ext_vector_type(2))) float f32x2;

__device__ __forceinline__ float fast_rcp(float x) {
#if __has_builtin(__builtin_amdgcn_rcpf)
  return __builtin_amdgcn_rcpf(x);
#else
  return 1.0f / x;
#endif
}
__device__ __forceinline__ float EX2(float x) {
#if __has_builtin(__builtin_amdgcn_exp2f)
  return __builtin_amdgcn_exp2f(x);
#else
  return exp2f(x);
#endif
}
__device__ __forceinline__ float LG2(float x) {
#if __has_builtin(__builtin_amdgcn_logf)
  return __builtin_amdgcn_logf(x);  // log2
#else
  return log2f(x);
#endif
}
__device__ __forceinline__ unsigned f2bf(float x) {
  unsigned u = __float_as_uint(x);
  return (u + 0x7fffu + ((u >> 16) & 1u)) >> 16;
}
__device__ __forceinline__ float u2f(unsigned u) { return __uint_as_float(u); }
__device__ __forceinline__ f32x2 mk2(float a, float b) {
  f32x2 r; r.x = a; r.y = b; return r;
}
// unpack u32 holding (lo u16 -> ch0 bf16, hi u16 -> ch1 bf16) to f32x2
__device__ __forceinline__ f32x2 unp(unsigned u) {
  return mk2(u2f(u << 16), u2f(u & 0xffff0000u));
}
// msg pair: sigm (exp2 dom, gf pre-scaled -log2e) * softplus (gs pre-scaled +log2e)
__device__ __forceinline__ void edge_ch2(f32x2 gf, f32x2 gs, float cmul, f32x2& acc) {
  f32x2 den = mk2(EX2(gf.x), EX2(gf.y)) + 1.0f;
  f32x2 lg = mk2(LG2(1.0f + EX2(-fabsf(gs.x))), LG2(1.0f + EX2(-fabsf(gs.y))));
  f32x2 sp = lg + __builtin_elementwise_max(gs, (f32x2)0.0f);
  f32x2 rt = mk2(fast_rcp(den.x), fast_rcp(den.y)) * sp;
  acc = __builtin_elementwise_fma(rt, (f32x2)cmul, acc);
}

// xf rows, bf16 rows, and pos4 in one pass (64 thr/node)
__global__ void init_x(const int* __restrict__ atoms, const float* __restrict__ pos,
                       const float* __restrict__ emb, float* __restrict__ xf,
                       unsigned* __restrict__ xbu, float4* __restrict__ pos4) {
  int n = blockIdx.x;
  int t = threadIdx.x;
  int a = atoms[n];
  float2 e = *(const float2*)(emb + (size_t)a * 128 + 2 * t);
  xf[(size_t)n * XS + 2 * t] = e.x;
  xf[(size_t)n * XS + 2 * t + 1] = e.y;
  xbu[(size_t)n * 64 + t] = f2bf(e.x) | (f2bf(e.y) << 16);
  if (t == 0) xf[(size_t)n * XS + 128] = pos[n * 3 + 2];
  if (t == 1) pos4[n] = make_float4(pos[3 * n], pos[3 * n + 1], pos[3 * n + 2], 0.f);
}

// B in MFMA fragment order + W128 rank-1 rows, one kernel.
// Bp[((l*4+g)*9+ct)*4+ks][lane] = 8 bf16: B[k=ks*32+(lane>>4)*8+j][col=ct*16+(lane&15)]
__global__ void prep_b(const float* __restrict__ Wf, const float* __restrict__ Ws,
                       uint4* __restrict__ Bp, float* __restrict__ W128) {
  int idx = blockIdx.x * 256 + threadIdx.x;
  if (idx < 5 * 4 * 9 * 4 * 64) {
    int lane = idx & 63;
    int t = idx >> 6;
    int ks = t & 3; t >>= 2;
    int ct = t % 9; t /= 9;
    int g = t & 3;
    int l = t >> 2;
    const float* W = (g >= 2) ? Ws : Wf;
    int col = ct * 16 + (lane & 15);
    int kb = ks * 32 + (lane >> 4) * 8;
    unsigned u[4];
#pragma unroll
    for (int p = 0; p < 4; ++p) {
      unsigned lo = 0, hi = 0;
      if (col < 129) {
        int k0 = kb + 2 * p, k1 = k0 + 1;
        int r0 = (g & 1) ? 129 + k0 : k0;
        int r1 = (g & 1) ? 129 + k1 : k1;
        lo = f2bf(W[(size_t)(l * 259 + r0) * 129 + col]);
        hi = f2bf(W[(size_t)(l * 259 + r1) * 129 + col]);
      }
      u[p] = lo | (hi << 16);
    }
    Bp[idx] = make_uint4(u[0], u[1], u[2], u[3]);
  } else {
    int j = idx - 5 * 4 * 9 * 4 * 64;
    if (j >= 5 * 4 * 129) return;
    int c = j % 129;
    int t = j / 129;
    int g = t & 3;
    int l = t >> 2;
    const float* W = (g >= 2) ? Ws : Wf;
    int row = (g & 1) ? 257 : 128;
    W128[(l * 4 + g) * 129 + c] = W[(size_t)(l * 259 + row) * 129 + c];
  }
}

__global__ void build_csr(const int* __restrict__ ei, const float4* __restrict__ pos4,
                          int* __restrict__ cnt, int2* __restrict__ csr) {
  int e = blockIdx.x * 256 + threadIdx.x;
  if (e >= N_EDGES) return;
  int s = ei[e];
  int d = ei[N_EDGES + e];
  float4 ps = pos4[s];
  float4 pd = pos4[d];
  float dx = ps.x - pd.x, dy = ps.y - pd.y, dz = ps.z - pd.z;
  float ea = sqrtf(dx * dx + dy * dy + dz * dz);
  int p = atomicAdd(&cnt[d], 1);
  if (p < CAP) csr[d * CAP + p] = make_int2(s, __float_as_int(ea));
}

// graph start offsets from sorted batch; goff[256]=N sentinel
__global__ void offsets_k(const int* __restrict__ batch, int* __restrict__ goff) {
  int n = blockIdx.x * 256 + threadIdx.x;
  if (n > N_NODES) return;
  int b = (n < N_NODES) ? batch[n] : NUM_GRAPHS;
  int bp = (n > 0) ? batch[n - 1] : -1;
  for (int g = bp + 1; g <= b; ++g) goff[g] = n;
}

// 32 rows x (4 groups x 144 cols) per block; wave w = group w.
// f-side (g0,g1) scaled by SCLN; s-side (g2,g3) by SCLP.
// u16 row layout (256 u16): [f(2c),f(2c+1),s(2c),s(2c+1)] at c*4 — Pdh dst, Pfs src.
// ch128: Pd128c[n]=u32(f|s) dst, Pc128[n]=u32(f|s) src.
__global__ __launch_bounds__(256) void gemm_mfma(
    const unsigned* __restrict__ xbu, const float* __restrict__ xf,
    const uint4* __restrict__ Bp, const float* __restrict__ W128,
    const float* __restrict__ bfL, const float* __restrict__ bsL,
    unsigned short* __restrict__ Pdh, unsigned short* __restrict__ Pfs,
    unsigned* __restrict__ Pd128c, unsigned* __restrict__ Pc128, int layer) {
  __shared__ short smA[32 * 136];  // row stride 136 shorts (conflict-free b128)
  int n0 = blockIdx.x * 32;
  int tid = threadIdx.x;
  for (int ch = tid; ch < 512; ch += 256) {
    int row = ch >> 4, cq = ch & 15;
    *(uint4*)(&smA[row * 136 + cq * 8]) =
        *(const uint4*)(xbu + (size_t)(n0 + row) * 64 + cq * 4);
  }
  __syncthreads();
  int g = tid >> 6;
  int l = tid & 63;
  int q = l >> 4, c16 = l & 15;
  const short8* Bp8 = (const short8*)Bp;
  int bbase = (layer * 4 + g) * 9 * 4;
  f32x4 acc[2][9];
#pragma unroll
  for (int rt = 0; rt < 2; ++rt)
#pragma unroll
    for (int ct = 0; ct < 9; ++ct) acc[rt][ct] = (f32x4){0.f, 0.f, 0.f, 0.f};
#pragma unroll
  for (int ks = 0; ks < 4; ++ks) {
    short8 a0 = *(const short8*)(&smA[c16 * 136 + (ks * 4 + q) * 8]);
    short8 a1 = *(const short8*)(&smA[(16 + c16) * 136 + (ks * 4 + q) * 8]);
#pragma unroll
    for (int ct = 0; ct < 9; ++ct) {
      short8 b = Bp8[(size_t)(bbase + ct * 4 + ks) * 64 + l];
      acc[0][ct] = __builtin_amdgcn_mfma_f32_16x16x32_bf16(a0, b, acc[0][ct], 0, 0, 0);
      acc[1][ct] = __builtin_amdgcn_mfma_f32_16x16x32_bf16(a1, b, acc[1][ct], 0, 0, 0);
    }
  }
  const float* W1g = W128 + (layer * 4 + g) * 129;
  float x128[2][4];
#pragma unroll
  for (int rt = 0; rt < 2; ++rt)
#pragma unroll
    for (int r = 0; r < 4; ++r)
      x128[rt][r] = xf[(size_t)(n0 + rt * 16 + q * 4 + r) * XS + 128];
  float scale = (g < 2) ? SCLN : SCLP;
  unsigned short* dstp = (g & 1) ? Pfs : Pdh;
  int soff = (g >= 2) ? 2 : 0;
  unsigned short* c128p = (g & 1) ? (unsigned short*)Pc128 : (unsigned short*)Pd128c;
  int c128o = (g >= 2) ? 1 : 0;
#pragma unroll
  for (int ct = 0; ct < 9; ++ct) {
    int col = ct * 16 + c16;
    float w1 = (col <= 128) ? W1g[col] : 0.0f;
    float bias = 0.0f;
    if (g == 0 && col <= 128) bias = bfL[col];
    if (g == 2 && col <= 128) bias = bsL[col];
#pragma unroll
    for (int rt = 0; rt < 2; ++rt) {
#pragma unroll
      for (int r = 0; r < 4; ++r) {
        int row = n0 + rt * 16 + q * 4 + r;
        float v = scale * (acc[rt][ct][r] + x128[rt][r] * w1 + bias);
        unsigned short bv = (unsigned short)f2bf(v);
        if (col < 128) {
          dstp[(size_t)row * 256 + ((col >> 1) << 2) + soff + (col & 1)] = bv;
        } else if (col == 128) {
          c128p[2 * (size_t)row + c128o] = bv;
        }
      }
    }
  }
}

// one wave per dst node. Lanes 0-31: even edges, 32-63: odd edges; each lane 4 channels
// (4*l5..4*l5+3) via one uint4 gather. Cross-half combine by shfl_xor(32) at the end.
__global__ __launch_bounds__(256) void edge_agg(
    const unsigned short* __restrict__ Pdh, const unsigned short* __restrict__ Pfs,
    const unsigned* __restrict__ Pd128c, const unsigned* __restrict__ Pc128,
    float* __restrict__ xf, unsigned* __restrict__ xbu, const int* __restrict__ cnt,
    const int2* __restrict__ csr, const float* __restrict__ WfL,
    const float* __restrict__ WsL) {
  int lane = threadIdx.x & 63;
  int half = lane >> 5;
  int l5 = lane & 31;
  int n = blockIdx.x * 4 + (threadIdx.x >> 6);
  if (n >= N_NODES) return;
  int nu = __builtin_amdgcn_readfirstlane(n);  // wave-uniform -> scalar pipe
  const float* wfl = WfL + 258 * 129;
  const float* wsl = WsL + 258 * 129;
  uint4 pdv = *(const uint4*)(Pdh + (size_t)nu * 256 + 8 * l5);
  f32x2 bfa = unp(pdv.x), bsa = unp(pdv.y), bfb = unp(pdv.z), bsb = unp(pdv.w);
  float2 wfa0 = *(const float2*)(wfl + 4 * l5);
  float2 wfb0 = *(const float2*)(wfl + 4 * l5 + 2);
  float2 wsa0 = *(const float2*)(wsl + 4 * l5);
  float2 wsb0 = *(const float2*)(wsl + 4 * l5 + 2);
  f32x2 wfa = mk2(SCLN * wfa0.x, SCLN * wfa0.y), wfb = mk2(SCLN * wfb0.x, SCLN * wfb0.y);
  f32x2 wsa = mk2(SCLP * wsa0.x, SCLP * wsa0.y), wsb = mk2(SCLP * wsb0.x, SCLP * wsb0.y);
  unsigned pd1 = Pd128c[nu];
  float bfc8 = u2f(pd1 << 16), bsc8 = u2f(pd1 & 0xffff0000u);
  float wfc8 = SCLN * wfl[128], wsc8 = SCLP * wsl[128];
  int m = cnt[nu];
  if (m > CAP) m = CAP;
  const int4* cb4 = (const int4*)(csr + (size_t)nu * CAP);  // one pair of edges per int4
  float maskC = half ? 0.0f : C693;  // odd-tail: half 1 contributes 0
  f32x2 accA = (f32x2)0.0f, accB = (f32x2)0.0f;

#define DO_PAIR(qq, CM)                                                        \
  {                                                                            \
    int s_ = half ? qq.z : qq.x;                                               \
    f32x2 ea_ = (f32x2)__int_as_float(half ? qq.w : qq.y);                     \
    uint4 g_ = *(const uint4*)(Pfs + (size_t)s_ * 256 + 8 * l5);               \
    edge_ch2(__builtin_elementwise_fma(ea_, wfa, bfa + unp(g_.x)),             \
             __builtin_elementwise_fma(ea_, wsa, bsa + unp(g_.y)), CM, accA);  \
    edge_ch2(__builtin_elementwise_fma(ea_, wfb, bfb + unp(g_.z)),             \
             __builtin_elementwise_fma(ea_, wsb, bsb + unp(g_.w)), CM, accB);  \
  }

  int Pf = m >> 1;
  int p = 0;
  for (; p + 1 < Pf; p += 2) {
    int4 q0 = cb4[p];
    int4 q1 = cb4[p + 1];
    DO_PAIR(q0, C693);
    DO_PAIR(q1, C693);
  }
  if (p < Pf) {
    int4 q0 = cb4[p];
    DO_PAIR(q0, C693);
  }
  if (m & 1) {  // last edge: both halves compute it, half 1 masked to zero
    int4 q = cb4[Pf];
    int s_ = q.x;
    f32x2 ea_ = (f32x2)__int_as_float(q.y);
    uint4 g_ = *(const uint4*)(Pfs + (size_t)s_ * 256 + 8 * l5);
    edge_ch2(__builtin_elementwise_fma(ea_, wfa, bfa + unp(g_.x)),
             __builtin_elementwise_fma(ea_, wsa, bsa + unp(g_.y)), maskC, accA);
    edge_ch2(__builtin_elementwise_fma(ea_, wfb, bfb + unp(g_.z)),
             __builtin_elementwise_fma(ea_, wsb, bsb + unp(g_.w)), maskC, accB);
  }
#undef DO_PAIR

  // combine halves
  accA.x += __shfl_xor(accA.x, 32, 64);
  accA.y += __shfl_xor(accA.y, 32, 64);
  accB.x += __shfl_xor(accB.x, 32, 64);
  accB.y += __shfl_xor(accB.y, 32, 64);

  // channel 128: lanes parallel over edges (deg <= 64), single u32 gather, reduce
  float v2 = 0.f;
  if (lane < m) {
    int2 se = csr[(size_t)nu * CAP + lane];
    float ea = __int_as_float(se.y);
    unsigned pc = Pc128[se.x];
    float f2 = u2f(pc << 16), s2 = u2f(pc & 0xffff0000u);
    float gf2 = fmaf(ea, wfc8, bfc8 + f2);
    float gs2 = fmaf(ea, wsc8, bsc8 + s2);
    float sp2 = LG2(1.0f + EX2(-fabsf(gs2))) + fmaxf(gs2, 0.0f);
    v2 = C693 * fast_rcp(1.0f + EX2(gf2)) * sp2;
  }
#pragma unroll
  for (int off = 32; off; off >>= 1) v2 += __shfl_down(v2, off, 64);

  size_t xo = (size_t)nu * XS;
  if (half == 0) {
    float4 xv = *(const float4*)(xf + xo + 4 * l5);
    float4 res = make_float4(xv.x + accA.x, xv.y + accA.y, xv.z + accB.x, xv.w + accB.y);
    *(float4*)(xf + xo + 4 * l5) = res;
    *(uint2*)(xbu + (size_t)nu * 64 + 2 * l5) =
        make_uint2(f2bf(res.x) | (f2bf(res.y) << 16), f2bf(res.z) | (f2bf(res.w) << 16));
  }
  if (lane == 0) xf[xo + 128] += v2;
}

// 4 blocks per graph, partial sums + light atomics; gsum pre-zeroed
__global__ void pool2(const float* __restrict__ xf, const int* __restrict__ goff,
                      float* __restrict__ gsum) {
  int gph = blockIdx.x >> 2;
  int q = blockIdx.x & 3;
  int t = threadIdx.x;
  if (t >= 129) return;
  int s = goff[gph], e = goff[gph + 1];
  int len = e - s;
  int chunk = (len + 3) >> 2;
  int a = s + q * chunk;
  int b = a + chunk; if (b > e) b = e;
  if (a >= b) return;
  float acc = 0.f;
  for (int n = a; n < b; ++n) acc += xf[(size_t)n * XS + t];
  atomicAdd(&gsum[gph * XS + t], acc);
}

// fused: mean-divide + fc1 + fc2 + fc3 + out. one block per graph, 192 thr.
__global__ void fcout(const float* __restrict__ gsum, const int* __restrict__ goff,
                      const float* __restrict__ Wfc, const float* __restrict__ bfc,
                      const float* __restrict__ Wout, const float* __restrict__ bout,
                      float* __restrict__ out) {
  __shared__ float buf[2][132];
  __shared__ float red[3];
  int i = blockIdx.x;
  int t = threadIdx.x;
  int len = goff[i + 1] - goff[i];
  float inv = fast_rcp(fmaxf((float)len, 1.0f));
  if (t < 129) buf[0][t] = gsum[i * XS + t] * inv;
  __syncthreads();
  int cur = 0;
#pragma unroll
  for (int l = 0; l < 3; ++l) {
    float s = 0.f;
    if (t < 129) {
      s = bfc[l * 129 + t];
      const float* W = Wfc + (size_t)l * 129 * 129;
#pragma unroll 4
      for (int k = 0; k < 129; ++k) s += buf[cur][k] * W[k * 129 + t];
    }
    __syncthreads();
    if (t < 129) buf[1 - cur][t] = s;
    cur = 1 - cur;
    __syncthreads();
  }
  float p = (t < 129) ? buf[cur][t] * Wout[t] : 0.f;
#pragma unroll
  for (int off = 32; off; off >>= 1) p += __shfl_down(p, off, 64);
  if ((t & 63) == 0) red[t >> 6] = p;
  __syncthreads();
  if (t == 0) out[i] = red[0] + red[1] + red[2] + bout[0];
}

extern "C" void kernel_launch(void* const* d_in, const int* in_sizes, int n_in,
                              void* d_out, int out_size, void* d_ws, size_t ws_size,
                              hipStream_t stream) {
  const int* atoms = (const int*)d_in[0];
  const float* pos = (const float*)d_in[1];
  const int* ei = (const int*)d_in[2];
  const int* batch = (const int*)d_in[3];
  const float* emb = (const float*)d_in[4];
  const float* Wf = (const float*)d_in[5];
  const float* bfp = (const float*)d_in[6];
  const float* Ws = (const float*)d_in[7];
  const float* bsp = (const float*)d_in[8];
  const float* Wfc = (const float*)d_in[9];
  const float* bfc = (const float*)d_in[10];
  const float* Wout = (const float*)d_in[11];
  const float* bout = (const float*)d_in[12];
  float* outp = (float*)d_out;

  // workspace layout (every array 16B-aligned by construction)
  uint4* Bp = (uint4*)d_ws;                                   // 46080 uint4
  float* xf = (float*)(Bp + 46080);                           // NPADROWS*132 f32
  unsigned* xbu = (unsigned*)(xf + (size_t)NPADROWS * XS);    // NPADROWS*64 u32
  unsigned short* Pdh = (unsigned short*)(xbu + (size_t)NPADROWS * 64);  // NPADROWS*256
  unsigned short* Pfs = Pdh + (size_t)NPADROWS * 256;         // NPADROWS*256
  float4* pos4 = (float4*)(Pfs + (size_t)NPADROWS * 256);     // N_NODES float4
  float* W128 = (float*)(pos4 + N_NODES);                     // 2580
  float* gsum = W128 + 2580;                                  // 256*132
  int* goff = (int*)(gsum + 256 * XS);                        // 260 (padded)
  int* cnt = goff + 260;                                      // N_NODES
  int2* csr = (int2*)(cnt + N_NODES);                         // N_NODES*CAP (16B-aligned)
  unsigned* Pd128c = (unsigned*)(csr + (size_t)N_NODES * CAP);  // NPADROWS u32
  unsigned* Pc128 = Pd128c + NPADROWS;                        // NPADROWS u32

  hipMemsetAsync(cnt, 0, N_NODES * sizeof(int), stream);
  hipMemsetAsync(gsum, 0, 256 * XS * sizeof(float), stream);

  init_x<<<N_NODES, 64, 0, stream>>>(atoms, pos, emb, xf, xbu, pos4);
  prep_b<<<(5 * 4 * 9 * 4 * 64 + 5 * 4 * 129 + 255) / 256, 256, 0, stream>>>(Wf, Ws, Bp,
                                                                             W128);
  build_csr<<<(N_EDGES + 255) / 256, 256, 0, stream>>>(ei, pos4, cnt, csr);
  offsets_k<<<(N_NODES + 256) / 256, 256, 0, stream>>>(batch, goff);

  for (int l = 0; l < 5; ++l) {
    gemm_mfma<<<NPADROWS / 32, 256, 0, stream>>>(xbu, xf, Bp, W128, bfp + l * 129,
                                                 bsp + l * 129, Pdh, Pfs, Pd128c,
                                                 Pc128, l);
    edge_agg<<<(N_NODES + 3) / 4, 256, 0, stream>>>(Pdh, Pfs, Pd128c, Pc128, xf, xbu,
                                                    cnt, csr,
                                                    Wf + (size_t)l * 259 * 129,
                                                    Ws + (size_t)l * 259 * 129);
  }

  pool2<<<NUM_GRAPHS * 4, 192, 0, stream>>>(xf, goff, gsum);
  fcout<<<NUM_GRAPHS, 192, 0, stream>>>(gsum, goff, Wfc, bfc, Wout, bout, outp);
}

// Round 8
// 738.604 us; speedup vs baseline: 2.4566x; 1.0257x over previous
//
#include <hip/hip_runtime.h>
#include <math.h>

#define N_NODES 50000
#define N_EDGES 800000
#define NUM_GRAPHS 256
#define NPADROWS 50048   // 1564*32
#define CAP 64           // CSR capacity per node (max observed degree ~35)
#define XS 132           // xf row stride (floats); [0..127]=emb ch, [128]=z
#define SCLN -1.44269504088896f  // -log2(e): f-side scale, exp2(SCLN*x)=exp(-x)
#define SCLP 1.44269504088896f   // +log2(e): s-side scale
#define C693 0.69314718056f
#define LROW 264         // LDS staging row stride in u16 (528 B, 16B-aligned, bank-skewed)

typedef __attribute__((ext_vector_type(8))) short short8;
typedef __attribute__((ext_vector_type(4))) float f32x4;
typedef __attribute__((ext_vector_type(2))) float f32x2;

__device__ __forceinline__ float fast_rcp(float x) {
#if __has_builtin(__builtin_amdgcn_rcpf)
  return __builtin_amdgcn_rcpf(x);
#else
  return 1.0f / x;
#endif
}
__device__ __forceinline__ float EX2(float x) {
#if __has_builtin(__builtin_amdgcn_exp2f)
  return __builtin_amdgcn_exp2f(x);
#else
  return exp2f(x);
#endif
}
__device__ __forceinline__ float LG2(float x) {
#if __has_builtin(__builtin_amdgcn_logf)
  return __builtin_amdgcn_logf(x);  // log2
#else
  return log2f(x);
#endif
}
__device__ __forceinline__ unsigned f2bf(float x) {
  unsigned u = __float_as_uint(x);
  return (u + 0x7fffu + ((u >> 16) & 1u)) >> 16;
}
__device__ __forceinline__ float u2f(unsigned u) { return __uint_as_float(u); }
__device__ __forceinline__ f32x2 mk2(float a, float b) {
  f32x2 r; r.x = a; r.y = b; return r;
}
// unpack u32 holding (lo u16 -> ch0 bf16, hi u16 -> ch1 bf16) to f32x2
__device__ __forceinline__ f32x2 unp(unsigned u) {
  return mk2(u2f(u << 16), u2f(u & 0xffff0000u));
}
// msg pair: sigm (exp2 dom, gf pre-scaled -log2e) * softplus (gs pre-scaled +log2e)
__device__ __forceinline__ void edge_ch2(f32x2 gf, f32x2 gs, float cmul, f32x2& acc) {
  f32x2 den = mk2(EX2(gf.x), EX2(gf.y)) + 1.0f;
  f32x2 lg = mk2(LG2(1.0f + EX2(-fabsf(gs.x))), LG2(1.0f + EX2(-fabsf(gs.y))));
  f32x2 sp = lg + __builtin_elementwise_max(gs, (f32x2)0.0f);
  f32x2 rt = mk2(fast_rcp(den.x), fast_rcp(den.y)) * sp;
  acc = __builtin_elementwise_fma(rt, (f32x2)cmul, acc);
}

// xf rows, bf16 rows, and pos4 in one pass (64 thr/node)
__global__ void init_x(const int* __restrict__ atoms, const float* __restrict__ pos,
                       const float* __restrict__ emb, float* __restrict__ xf,
                       unsigned* __restrict__ xbu, float4* __restrict__ pos4) {
  int n = blockIdx.x;
  int t = threadIdx.x;
  int a = atoms[n];
  float2 e = *(const float2*)(emb + (size_t)a * 128 + 2 * t);
  xf[(size_t)n * XS + 2 * t] = e.x;
  xf[(size_t)n * XS + 2 * t + 1] = e.y;
  xbu[(size_t)n * 64 + t] = f2bf(e.x) | (f2bf(e.y) << 16);
  if (t == 0) xf[(size_t)n * XS + 128] = pos[n * 3 + 2];
  if (t == 1) pos4[n] = make_float4(pos[3 * n], pos[3 * n + 1], pos[3 * n + 2], 0.f);
}

// B in MFMA fragment order + W128 rank-1 rows, one kernel.
// Bp[((l*4+g)*9+ct)*4+ks][lane] = 8 bf16: B[k=ks*32+(lane>>4)*8+j][col=ct*16+(lane&15)]
__global__ void prep_b(const float* __restrict__ Wf, const float* __restrict__ Ws,
                       uint4* __restrict__ Bp, float* __restrict__ W128) {
  int idx = blockIdx.x * 256 + threadIdx.x;
  if (idx < 5 * 4 * 9 * 4 * 64) {
    int lane = idx & 63;
    int t = idx >> 6;
    int ks = t & 3; t >>= 2;
    int ct = t % 9; t /= 9;
    int g = t & 3;
    int l = t >> 2;
    const float* W = (g >= 2) ? Ws : Wf;
    int col = ct * 16 + (lane & 15);
    int kb = ks * 32 + (lane >> 4) * 8;
    unsigned u[4];
#pragma unroll
    for (int p = 0; p < 4; ++p) {
      unsigned lo = 0, hi = 0;
      if (col < 129) {
        int k0 = kb + 2 * p, k1 = k0 + 1;
        int r0 = (g & 1) ? 129 + k0 : k0;
        int r1 = (g & 1) ? 129 + k1 : k1;
        lo = f2bf(W[(size_t)(l * 259 + r0) * 129 + col]);
        hi = f2bf(W[(size_t)(l * 259 + r1) * 129 + col]);
      }
      u[p] = lo | (hi << 16);
    }
    Bp[idx] = make_uint4(u[0], u[1], u[2], u[3]);
  } else {
    int j = idx - 5 * 4 * 9 * 4 * 64;
    if (j >= 5 * 4 * 129) return;
    int c = j % 129;
    int t = j / 129;
    int g = t & 3;
    int l = t >> 2;
    const float* W = (g >= 2) ? Ws : Wf;
    int row = (g & 1) ? 257 : 128;
    W128[(l * 4 + g) * 129 + c] = W[(size_t)(l * 259 + row) * 129 + c];
  }
}

__global__ void build_csr(const int* __restrict__ ei, const float4* __restrict__ pos4,
                          int* __restrict__ cnt, int2* __restrict__ csr) {
  int e = blockIdx.x * 256 + threadIdx.x;
  if (e >= N_EDGES) return;
  int s = ei[e];
  int d = ei[N_EDGES + e];
  float4 ps = pos4[s];
  float4 pd = pos4[d];
  float dx = ps.x - pd.x, dy = ps.y - pd.y, dz = ps.z - pd.z;
  float ea = sqrtf(dx * dx + dy * dy + dz * dz);
  int p = atomicAdd(&cnt[d], 1);
  if (p < CAP) csr[d * CAP + p] = make_int2(s, __float_as_int(ea));
}

// graph start offsets from sorted batch; goff[256]=N sentinel
__global__ void offsets_k(const int* __restrict__ batch, int* __restrict__ goff) {
  int n = blockIdx.x * 256 + threadIdx.x;
  if (n > N_NODES) return;
  int b = (n < N_NODES) ? batch[n] : NUM_GRAPHS;
  int bp = (n > 0) ? batch[n - 1] : -1;
  for (int g = bp + 1; g <= b; ++g) goff[g] = n;
}

// 32 rows x (4 groups x 144 cols) per block; wave w = group w.
// f-side (g0,g1) scaled by SCLN; s-side (g2,g3) by SCLP.
// u16 row layout (256 u16): [f(2c),f(2c+1),s(2c),s(2c+1)] at c*4 — Pdh dst, Pfs src.
// ch128: Pd128c[n]=u32(f|s) dst, Pc128[n]=u32(f|s) src.
// Output staged via LDS row-images -> coalesced dwordx4 stores.
__global__ __launch_bounds__(256) void gemm_mfma(
    const unsigned* __restrict__ xbu, const float* __restrict__ xf,
    const uint4* __restrict__ Bp, const float* __restrict__ W128,
    const float* __restrict__ bfL, const float* __restrict__ bsL,
    unsigned short* __restrict__ Pdh, unsigned short* __restrict__ Pfs,
    unsigned* __restrict__ Pd128c, unsigned* __restrict__ Pc128, int layer) {
  __shared__ short smA[32 * 136];  // A staging, row stride 136 shorts
  __shared__ unsigned short ldsD[32 * LROW];  // dst row image (f+s interleaved)
  __shared__ unsigned short ldsS[32 * LROW];  // src row image
  int n0 = blockIdx.x * 32;
  int tid = threadIdx.x;
  for (int ch = tid; ch < 512; ch += 256) {
    int row = ch >> 4, cq = ch & 15;
    *(uint4*)(&smA[row * 136 + cq * 8]) =
        *(const uint4*)(xbu + (size_t)(n0 + row) * 64 + cq * 4);
  }
  __syncthreads();
  int g = tid >> 6;
  int l = tid & 63;
  int q = l >> 4, c16 = l & 15;
  const short8* Bp8 = (const short8*)Bp;
  int bbase = (layer * 4 + g) * 9 * 4;
  f32x4 acc[2][9];
#pragma unroll
  for (int rt = 0; rt < 2; ++rt)
#pragma unroll
    for (int ct = 0; ct < 9; ++ct) acc[rt][ct] = (f32x4){0.f, 0.f, 0.f, 0.f};
#pragma unroll
  for (int ks = 0; ks < 4; ++ks) {
    short8 a0 = *(const short8*)(&smA[c16 * 136 + (ks * 4 + q) * 8]);
    short8 a1 = *(const short8*)(&smA[(16 + c16) * 136 + (ks * 4 + q) * 8]);
#pragma unroll
    for (int ct = 0; ct < 9; ++ct) {
      short8 b = Bp8[(size_t)(bbase + ct * 4 + ks) * 64 + l];
      acc[0][ct] = __builtin_amdgcn_mfma_f32_16x16x32_bf16(a0, b, acc[0][ct], 0, 0, 0);
      acc[1][ct] = __builtin_amdgcn_mfma_f32_16x16x32_bf16(a1, b, acc[1][ct], 0, 0, 0);
    }
  }
  const float* W1g = W128 + (layer * 4 + g) * 129;
  float x128[2][4];
#pragma unroll
  for (int rt = 0; rt < 2; ++rt)
#pragma unroll
    for (int r = 0; r < 4; ++r)
      x128[rt][r] = xf[(size_t)(n0 + rt * 16 + q * 4 + r) * XS + 128];
  float scale = (g < 2) ? SCLN : SCLP;
  unsigned short* ldsO = (g & 1) ? ldsS : ldsD;
  int soff = (g >= 2) ? 2 : 0;
  unsigned short* c128p = (g & 1) ? (unsigned short*)Pc128 : (unsigned short*)Pd128c;
  int c128o = (g >= 2) ? 1 : 0;
#pragma unroll
  for (int ct = 0; ct < 9; ++ct) {
    int col = ct * 16 + c16;
    float w1 = (col <= 128) ? W1g[col] : 0.0f;
    float bias = 0.0f;
    if (g == 0 && col <= 128) bias = bfL[col];
    if (g == 2 && col <= 128) bias = bsL[col];
#pragma unroll
    for (int rt = 0; rt < 2; ++rt) {
#pragma unroll
      for (int r = 0; r < 4; ++r) {
        int rl = rt * 16 + q * 4 + r;  // local row
        float v = scale * (acc[rt][ct][r] + x128[rt][r] * w1 + bias);
        unsigned short bv = (unsigned short)f2bf(v);
        if (col < 128) {
          ldsO[rl * LROW + ((col >> 1) << 2) + soff + (col & 1)] = bv;
        } else if (col == 128) {
          c128p[2 * (size_t)(n0 + rl) + c128o] = bv;
        }
      }
    }
  }
  __syncthreads();
  // coalesced writeback: 2048 16B-chunks (1024 per image), 8 rounds of 256 thr
#pragma unroll
  for (int i = tid; i < 2048; i += 256) {
    int img = i >> 10;
    int c = i & 1023;
    int row = c >> 5, part = c & 31;  // 32 x 16B per 512B row
    const unsigned short* src = (img ? ldsS : ldsD) + row * LROW + part * 8;
    unsigned short* dst = (img ? Pfs : Pdh) + (size_t)(n0 + row) * 256 + part * 8;
    *(uint4*)dst = *(const uint4*)src;
  }
}

// one wave per dst node. Lanes 0-31: even edges, 32-63: odd edges; each lane 4 channels
// (4*l5..4*l5+3) via one uint4 gather; depth-1 software pipeline on the gather.
__global__ __launch_bounds__(256) void edge_agg(
    const unsigned short* __restrict__ Pdh, const unsigned short* __restrict__ Pfs,
    const unsigned* __restrict__ Pd128c, const unsigned* __restrict__ Pc128,
    float* __restrict__ xf, unsigned* __restrict__ xbu, const int* __restrict__ cnt,
    const int2* __restrict__ csr, const float* __restrict__ WfL,
    const float* __restrict__ WsL) {
  int lane = threadIdx.x & 63;
  int half = lane >> 5;
  int l5 = lane & 31;
  int n = blockIdx.x * 4 + (threadIdx.x >> 6);
  if (n >= N_NODES) return;
  int nu = __builtin_amdgcn_readfirstlane(n);  // wave-uniform -> scalar pipe
  const float* wfl = WfL + 258 * 129;
  const float* wsl = WsL + 258 * 129;
  uint4 pdv = *(const uint4*)(Pdh + (size_t)nu * 256 + 8 * l5);
  f32x2 bfa = unp(pdv.x), bsa = unp(pdv.y), bfb = unp(pdv.z), bsb = unp(pdv.w);
  float2 wfa0 = *(const float2*)(wfl + 4 * l5);
  float2 wfb0 = *(const float2*)(wfl + 4 * l5 + 2);
  float2 wsa0 = *(const float2*)(wsl + 4 * l5);
  float2 wsb0 = *(const float2*)(wsl + 4 * l5 + 2);
  f32x2 wfa = mk2(SCLN * wfa0.x, SCLN * wfa0.y), wfb = mk2(SCLN * wfb0.x, SCLN * wfb0.y);
  f32x2 wsa = mk2(SCLP * wsa0.x, SCLP * wsa0.y), wsb = mk2(SCLP * wsb0.x, SCLP * wsb0.y);
  unsigned pd1 = Pd128c[nu];
  float bfc8 = u2f(pd1 << 16), bsc8 = u2f(pd1 & 0xffff0000u);
  float wfc8 = SCLN * wfl[128], wsc8 = SCLP * wsl[128];
  int m = cnt[nu];
  if (m > CAP) m = CAP;
  const int4* cb4 = (const int4*)(csr + (size_t)nu * CAP);  // one pair of edges per int4
  const uint4* Pfq = (const uint4*)Pfs;  // row = 32 uint4, lane chunk = +l5
  float maskC = half ? 0.0f : C693;  // odd-tail: half 1 contributes 0
  f32x2 accA = (f32x2)0.0f, accB = (f32x2)0.0f;

#define GATHER(qq) Pfq[(size_t)(half ? qq.z : qq.x) * 32 + l5]
#define COMPUTE(qq, gg, CM)                                                    \
  {                                                                            \
    f32x2 ea_ = (f32x2)__int_as_float(half ? qq.w : qq.y);                     \
    edge_ch2(__builtin_elementwise_fma(ea_, wfa, bfa + unp(gg.x)),             \
             __builtin_elementwise_fma(ea_, wsa, bsa + unp(gg.y)), CM, accA);  \
    edge_ch2(__builtin_elementwise_fma(ea_, wfb, bfb + unp(gg.z)),             \
             __builtin_elementwise_fma(ea_, wsb, bsb + unp(gg.w)), CM, accB);  \
  }

  int Pf = m >> 1;
  int4 qc = make_int4(0, 0, 0, 0);
  uint4 gc = make_uint4(0, 0, 0, 0);
  if (Pf > 0) {
    qc = cb4[0];
    gc = GATHER(qc);
  }
  for (int p = 0; p < Pf; ++p) {
    int4 qn = qc;
    uint4 gn = gc;
    if (p + 1 < Pf) {
      qn = cb4[p + 1];
      gn = GATHER(qn);
    }
    COMPUTE(qc, gc, C693);
    qc = qn;
    gc = gn;
  }
  if (m & 1) {  // last edge: both halves compute it, half 1 masked to zero
    int4 qt = cb4[Pf];
    f32x2 ea_ = (f32x2)__int_as_float(qt.y);
    uint4 gt = Pfq[(size_t)qt.x * 32 + l5];
    edge_ch2(__builtin_elementwise_fma(ea_, wfa, bfa + unp(gt.x)),
             __builtin_elementwise_fma(ea_, wsa, bsa + unp(gt.y)), maskC, accA);
    edge_ch2(__builtin_elementwise_fma(ea_, wfb, bfb + unp(gt.z)),
             __builtin_elementwise_fma(ea_, wsb, bsb + unp(gt.w)), maskC, accB);
  }
#undef GATHER
#undef COMPUTE

  // combine halves
  accA.x += __shfl_xor(accA.x, 32, 64);
  accA.y += __shfl_xor(accA.y, 32, 64);
  accB.x += __shfl_xor(accB.x, 32, 64);
  accB.y += __shfl_xor(accB.y, 32, 64);

  // channel 128: lanes parallel over edges (deg <= 64), single u32 gather, reduce
  float v2 = 0.f;
  if (lane < m) {
    int2 se = csr[(size_t)nu * CAP + lane];
    float ea = __int_as_float(se.y);
    unsigned pc = Pc128[se.x];
    float f2 = u2f(pc << 16), s2 = u2f(pc & 0xffff0000u);
    float gf2 = fmaf(ea, wfc8, bfc8 + f2);
    float gs2 = fmaf(ea, wsc8, bsc8 + s2);
    float sp2 = LG2(1.0f + EX2(-fabsf(gs2))) + fmaxf(gs2, 0.0f);
    v2 = C693 * fast_rcp(1.0f + EX2(gf2)) * sp2;
  }
#pragma unroll
  for (int off = 32; off; off >>= 1) v2 += __shfl_down(v2, off, 64);

  size_t xo = (size_t)nu * XS;
  if (half == 0) {
    float4 xv = *(const float4*)(xf + xo + 4 * l5);
    float4 res = make_float4(xv.x + accA.x, xv.y + accA.y, xv.z + accB.x, xv.w + accB.y);
    *(float4*)(xf + xo + 4 * l5) = res;
    *(uint2*)(xbu + (size_t)nu * 64 + 2 * l5) =
        make_uint2(f2bf(res.x) | (f2bf(res.y) << 16), f2bf(res.z) | (f2bf(res.w) << 16));
  }
  if (lane == 0) xf[xo + 128] += v2;
}

// 4 blocks per graph, partial sums + light atomics; gsum pre-zeroed
__global__ void pool2(const float* __restrict__ xf, const int* __restrict__ goff,
                      float* __restrict__ gsum) {
  int gph = blockIdx.x >> 2;
  int q = blockIdx.x & 3;
  int t = threadIdx.x;
  if (t >= 129) return;
  int s = goff[gph], e = goff[gph + 1];
  int len = e - s;
  int chunk = (len + 3) >> 2;
  int a = s + q * chunk;
  int b = a + chunk; if (b > e) b = e;
  if (a >= b) return;
  float acc = 0.f;
  for (int n = a; n < b; ++n) acc += xf[(size_t)n * XS + t];
  atomicAdd(&gsum[gph * XS + t], acc);
}

// fused: mean-divide + fc1 + fc2 + fc3 + out. one block per graph, 192 thr.
__global__ void fcout(const float* __restrict__ gsum, const int* __restrict__ goff,
                      const float* __restrict__ Wfc, const float* __restrict__ bfc,
                      const float* __restrict__ Wout, const float* __restrict__ bout,
                      float* __restrict__ out) {
  __shared__ float buf[2][132];
  __shared__ float red[3];
  int i = blockIdx.x;
  int t = threadIdx.x;
  int len = goff[i + 1] - goff[i];
  float inv = fast_rcp(fmaxf((float)len, 1.0f));
  if (t < 129) buf[0][t] = gsum[i * XS + t] * inv;
  __syncthreads();
  int cur = 0;
#pragma unroll
  for (int l = 0; l < 3; ++l) {
    float s = 0.f;
    if (t < 129) {
      s = bfc[l * 129 + t];
      const float* W = Wfc + (size_t)l * 129 * 129;
#pragma unroll 4
      for (int k = 0; k < 129; ++k) s += buf[cur][k] * W[k * 129 + t];
    }
    __syncthreads();
    if (t < 129) buf[1 - cur][t] = s;
    cur = 1 - cur;
    __syncthreads();
  }
  float p = (t < 129) ? buf[cur][t] * Wout[t] : 0.f;
#pragma unroll
  for (int off = 32; off; off >>= 1) p += __shfl_down(p, off, 64);
  if ((t & 63) == 0) red[t >> 6] = p;
  __syncthreads();
  if (t == 0) out[i] = red[0] + red[1] + red[2] + bout[0];
}

extern "C" void kernel_launch(void* const* d_in, const int* in_sizes, int n_in,
                              void* d_out, int out_size, void* d_ws, size_t ws_size,
                              hipStream_t stream) {
  const int* atoms = (const int*)d_in[0];
  const float* pos = (const float*)d_in[1];
  const int* ei = (const int*)d_in[2];
  const int* batch = (const int*)d_in[3];
  const float* emb = (const float*)d_in[4];
  const float* Wf = (const float*)d_in[5];
  const float* bfp = (const float*)d_in[6];
  const float* Ws = (const float*)d_in[7];
  const float* bsp = (const float*)d_in[8];
  const float* Wfc = (const float*)d_in[9];
  const float* bfc = (const float*)d_in[10];
  const float* Wout = (const float*)d_in[11];
  const float* bout = (const float*)d_in[12];
  float* outp = (float*)d_out;

  // workspace layout (every array 16B-aligned by construction)
  uint4* Bp = (uint4*)d_ws;                                   // 46080 uint4
  float* xf = (float*)(Bp + 46080);                           // NPADROWS*132 f32
  unsigned* xbu = (unsigned*)(xf + (size_t)NPADROWS * XS);    // NPADROWS*64 u32
  unsigned short* Pdh = (unsigned short*)(xbu + (size_t)NPADROWS * 64);  // NPADROWS*256
  unsigned short* Pfs = Pdh + (size_t)NPADROWS * 256;         // NPADROWS*256
  float4* pos4 = (float4*)(Pfs + (size_t)NPADROWS * 256);     // N_NODES float4
  float* W128 = (float*)(pos4 + N_NODES);                     // 2580
  float* gsum = W128 + 2580;                                  // 256*132
  int* goff = (int*)(gsum + 256 * XS);                        // 260 (padded)
  int* cnt = goff + 260;                                      // N_NODES
  int2* csr = (int2*)(cnt + N_NODES);                         // N_NODES*CAP (16B-aligned)
  unsigned* Pd128c = (unsigned*)(csr + (size_t)N_NODES * CAP);  // NPADROWS u32
  unsigned* Pc128 = Pd128c + NPADROWS;                        // NPADROWS u32

  hipMemsetAsync(cnt, 0, N_NODES * sizeof(int), stream);
  hipMemsetAsync(gsum, 0, 256 * XS * sizeof(float), stream);

  init_x<<<N_NODES, 64, 0, stream>>>(atoms, pos, emb, xf, xbu, pos4);
  prep_b<<<(5 * 4 * 9 * 4 * 64 + 5 * 4 * 129 + 255) / 256, 256, 0, stream>>>(Wf, Ws, Bp,
                                                                             W128);
  build_csr<<<(N_EDGES + 255) / 256, 256, 0, stream>>>(ei, pos4, cnt, csr);
  offsets_k<<<(N_NODES + 256) / 256, 256, 0, stream>>>(batch, goff);

  for (int l = 0; l < 5; ++l) {
    gemm_mfma<<<NPADROWS / 32, 256, 0, stream>>>(xbu, xf, Bp, W128, bfp + l * 129,
                                                 bsp + l * 129, Pdh, Pfs, Pd128c,
                                                 Pc128, l);
    edge_agg<<<(N_NODES + 3) / 4, 256, 0, stream>>>(Pdh, Pfs, Pd128c, Pc128, xf, xbu,
                                                    cnt, csr,
                                                    Wf + (size_t)l * 259 * 129,
                                                    Ws + (size_t)l * 259 * 129);
  }

  pool2<<<NUM_GRAPHS * 4, 192, 0, stream>>>(xf, goff, gsum);
  fcout<<<NUM_GRAPHS, 192, 0, stream>>>(gsum, goff, Wfc, bfc, Wout, bout, outp);
}